// Round 2
// baseline (1268.913 us; speedup 1.0000x reference)
//
#include <hip/hip_runtime.h>
#include <hip/hip_bf16.h>
#include <math.h>

// ---------------------------------------------------------------------------
// OGCNConv: x_x = x@W_sl+b_sl ; x_n = GCN_0(x) ; x_d = GCN_1(x)
// gat = cumsum(softmax([x_x|x_n|x_d]@W_g + b_g)) ; out = rev(x_d)*gat + x_x + x_n
// Indices arrive as int32 (harness converts int64 -> int32).
// ---------------------------------------------------------------------------

__global__ __launch_bounds__(256) void count_deg(const int* __restrict__ col,
                                                 const int* __restrict__ etype,
                                                 float* __restrict__ deg,  // [2n], zeroed
                                                 int E, int n) {
  int e = blockIdx.x * 256 + threadIdx.x;
  if (e >= E) return;
  int c = col[e];
  int t = etype[e];
  unsafeAtomicAdd(&deg[(size_t)t * n + c], 1.0f);
}

__global__ __launch_bounds__(256) void dinv_kernel(float* __restrict__ deg, int n2) {
  int i = blockIdx.x * 256 + threadIdx.x;
  if (i < n2) deg[i] = rsqrtf(deg[i] + 1.0f);  // +1 self-loop; deg>=1 always
}

// out = x @ W (+bias if bias!=null). 64-row tile/block, 8x4 register tile/thread.
__global__ __launch_bounds__(256) void gemm_xw(const float* __restrict__ x,
                                               const float* __restrict__ W,
                                               const float* __restrict__ bias,
                                               float* __restrict__ out, int n) {
  int row0 = blockIdx.x * 64;
  __shared__ float xs[64][128];  // 32 KB
  int tid = threadIdx.x;
  {
    const float4* xg = (const float4*)(x + (size_t)row0 * 128);
    float4* xl = (float4*)xs;
    int maxv = (n - row0) * 32;
#pragma unroll
    for (int i = 0; i < 8; ++i) {
      int idx = tid + i * 256;
      float4 v = {0.f, 0.f, 0.f, 0.f};
      if (idx < maxv) v = xg[idx];
      xl[idx] = v;
    }
  }
  __syncthreads();
  int c4 = tid & 31;   // column group: cols 4*c4..4*c4+3
  int tr = tid >> 5;   // row group: rows tr*8..tr*8+7
  const float4* W4 = (const float4*)W;
  float acc[8][4] = {};
#pragma unroll 4
  for (int k = 0; k < 128; ++k) {
    float4 w = W4[k * 32 + c4];
#pragma unroll
    for (int i = 0; i < 8; ++i) {
      float a = xs[tr * 8 + i][k];
      acc[i][0] = fmaf(a, w.x, acc[i][0]);
      acc[i][1] = fmaf(a, w.y, acc[i][1]);
      acc[i][2] = fmaf(a, w.z, acc[i][2]);
      acc[i][3] = fmaf(a, w.w, acc[i][3]);
    }
  }
  float4 bv = {0.f, 0.f, 0.f, 0.f};
  if (bias) bv = ((const float4*)bias)[c4];
#pragma unroll
  for (int i = 0; i < 8; ++i) {
    int r = row0 + tr * 8 + i;
    if (r < n) {
      float4 o;
      o.x = acc[i][0] + bv.x;
      o.y = acc[i][1] + bv.y;
      o.z = acc[i][2] + bv.z;
      o.w = acc[i][3] + bv.w;
      ((float4*)(out + (size_t)r * 128))[c4] = o;
    }
  }
}

// Per edge of type t: agg[col] += h[row] * dinv[row]*dinv[col].  32 threads/edge.
__global__ __launch_bounds__(256) void scatter(const int* __restrict__ row,
                                               const int* __restrict__ col,
                                               const int* __restrict__ etype,
                                               const float* __restrict__ h,
                                               const float* __restrict__ dinv,  // [n] for this t
                                               float* __restrict__ agg, int E, int t) {
  long long gid = (long long)blockIdx.x * 256 + threadIdx.x;
  int e = (int)(gid >> 5);
  if (e >= E) return;
  if (etype[e] != t) return;
  int f4 = (int)(gid & 31);
  int r = row[e];
  int c = col[e];
  float nrm = dinv[r] * dinv[c];
  float4 v = ((const float4*)(h + (size_t)r * 128))[f4];
  float* dst = agg + (size_t)c * 128 + (size_t)f4 * 4;
  unsafeAtomicAdd(dst + 0, v.x * nrm);
  unsafeAtomicAdd(dst + 1, v.y * nrm);
  unsafeAtomicAdd(dst + 2, v.z * nrm);
  unsafeAtomicAdd(dst + 3, v.w * nrm);
}

// agg = agg + h*dinv^2 + b  (self-loop contribution + bias), in place.
__global__ __launch_bounds__(256) void finalize(const float* __restrict__ h,
                                                const float* __restrict__ dinv,
                                                const float* __restrict__ b,
                                                float* __restrict__ agg, int n) {
  long long gid = (long long)blockIdx.x * 256 + threadIdx.x;
  int i = (int)(gid >> 5);
  if (i >= n) return;
  int f4 = (int)(gid & 31);
  float d = dinv[i];
  float s = d * d;
  size_t o = (size_t)i * 32 + f4;
  float4 a = ((const float4*)agg)[o];
  float4 v = ((const float4*)h)[o];
  float4 bb = ((const float4*)b)[f4];
  a.x += v.x * s + bb.x;
  a.y += v.y * s + bb.y;
  a.z += v.z * s + bb.z;
  a.w += v.w * s + bb.w;
  ((float4*)agg)[o] = a;
}

// logits = xx@Wg[0:128] + xn@Wg[128:256] + xd@Wg[256:384] + bg
__global__ __launch_bounds__(256) void gemm_gate(const float* __restrict__ xx,
                                                 const float* __restrict__ xn,
                                                 const float* __restrict__ xd,
                                                 const float* __restrict__ Wg,
                                                 const float* __restrict__ bg,
                                                 float* __restrict__ logits, int n) {
  int row0 = blockIdx.x * 64;
  __shared__ float xs[64][128];
  int tid = threadIdx.x;
  int c4 = tid & 31;
  int tr = tid >> 5;
  float acc[8][4] = {};
  int maxv = (n - row0) * 32;
  for (int seg = 0; seg < 3; ++seg) {
    const float* A = (seg == 0) ? xx : (seg == 1) ? xn : xd;
    const float4* xg = (const float4*)(A + (size_t)row0 * 128);
    float4* xl = (float4*)xs;
    __syncthreads();
#pragma unroll
    for (int i = 0; i < 8; ++i) {
      int idx = tid + i * 256;
      float4 v = {0.f, 0.f, 0.f, 0.f};
      if (idx < maxv) v = xg[idx];
      xl[idx] = v;
    }
    __syncthreads();
    const float4* W4 = (const float4*)(Wg + (size_t)seg * 128 * 128);
#pragma unroll 4
    for (int k = 0; k < 128; ++k) {
      float4 w = W4[k * 32 + c4];
#pragma unroll
      for (int i = 0; i < 8; ++i) {
        float a = xs[tr * 8 + i][k];
        acc[i][0] = fmaf(a, w.x, acc[i][0]);
        acc[i][1] = fmaf(a, w.y, acc[i][1]);
        acc[i][2] = fmaf(a, w.z, acc[i][2]);
        acc[i][3] = fmaf(a, w.w, acc[i][3]);
      }
    }
  }
  float4 bias = ((const float4*)bg)[c4];
#pragma unroll
  for (int i = 0; i < 8; ++i) {
    int r = row0 + tr * 8 + i;
    if (r < n) {
      float4 o;
      o.x = acc[i][0] + bias.x;
      o.y = acc[i][1] + bias.y;
      o.z = acc[i][2] + bias.z;
      o.w = acc[i][3] + bias.w;
      ((float4*)(logits + (size_t)r * 128))[c4] = o;
    }
  }
}

// Per node (one wave): softmax over 128 logits, cumsum, combine.
// out buffer doubles as xx input (read-before-write within the wave's own node).
__global__ __launch_bounds__(256) void combine(const float* __restrict__ logits,
                                               const float* __restrict__ xn,
                                               const float* __restrict__ xd,
                                               float* __restrict__ out, int n) {
  int wid = (int)(((long long)blockIdx.x * 256 + threadIdx.x) >> 6);
  int lane = threadIdx.x & 63;
  if (wid >= n) return;
  size_t base = (size_t)wid * 128;
  float a = logits[base + lane];
  float b = logits[base + 64 + lane];
  float m = fmaxf(a, b);
#pragma unroll
  for (int o = 32; o; o >>= 1) m = fmaxf(m, __shfl_xor(m, o));
  a = __expf(a - m);
  b = __expf(b - m);
  float s = a + b;
#pragma unroll
  for (int o = 32; o; o >>= 1) s += __shfl_xor(s, o);
  float inv = 1.0f / s;
  a *= inv;
  b *= inv;
  // inclusive scan of a (features 0..63) and b (features 64..127)
  float pa = a;
#pragma unroll
  for (int o = 1; o < 64; o <<= 1) {
    float t = __shfl_up(pa, o);
    if (lane >= o) pa += t;
  }
  float Sa = __shfl(pa, 63);
  float pb = b;
#pragma unroll
  for (int o = 1; o < 64; o <<= 1) {
    float t = __shfl_up(pb, o);
    if (lane >= o) pb += t;
  }
  float xx_a = out[base + lane];
  float xx_b = out[base + 64 + lane];
  float xn_a = xn[base + lane];
  float xn_b = xn[base + 64 + lane];
  float xd_ra = xd[base + 127 - lane];  // reversed
  float xd_rb = xd[base + 63 - lane];
  float oa = xd_ra * pa + xx_a + xn_a;
  float ob = xd_rb * (Sa + pb) + xx_b + xn_b;
  out[base + lane] = oa;
  out[base + 64 + lane] = ob;
}

extern "C" void kernel_launch(void* const* d_in, const int* in_sizes, int n_in,
                              void* d_out, int out_size, void* d_ws, size_t ws_size,
                              hipStream_t stream) {
  const float* x = (const float*)d_in[0];
  const int* eidx = (const int*)d_in[1];
  const int* etype = (const int*)d_in[2];
  const float* Wsl = (const float*)d_in[3];
  const float* bsl = (const float*)d_in[4];
  const float* W0 = (const float*)d_in[5];
  const float* b0 = (const float*)d_in[6];
  const float* W1 = (const float*)d_in[7];
  const float* b1 = (const float*)d_in[8];
  const float* Wg = (const float*)d_in[9];
  const float* bg = (const float*)d_in[10];
  int n = in_sizes[0] / 128;
  int E = in_sizes[2];
  const int* row = eidx;
  const int* col = eidx + E;

  // Workspace layout (floats): deg[2n] | xn[128n] | xd[128n] | h[128n]
  float* ws = (float*)d_ws;
  float* deg = ws;
  float* xn = ws + 2 * (size_t)n;
  float* xd = xn + 128 * (size_t)n;
  float* h = xd + 128 * (size_t)n;
  float* xx = (float*)d_out;
  float* logits = h;  // reuse h buffer for gate logits after both relations done

  // zero deg + xn + xd (contiguous)
  hipMemsetAsync(deg, 0, (2 + 256) * (size_t)n * sizeof(float), stream);

  count_deg<<<(E + 255) / 256, 256, 0, stream>>>(col, etype, deg, E, n);
  dinv_kernel<<<(2 * n + 255) / 256, 256, 0, stream>>>(deg, 2 * n);

  int gemm_blocks = (n + 63) / 64;
  long long sc_threads = (long long)E * 32;
  int sc_blocks = (int)((sc_threads + 255) / 256);
  int nf_blocks = (int)(((long long)n * 32 + 255) / 256);

  // relation 0
  gemm_xw<<<gemm_blocks, 256, 0, stream>>>(x, W0, nullptr, h, n);
  scatter<<<sc_blocks, 256, 0, stream>>>(row, col, etype, h, deg, xn, E, 0);
  finalize<<<nf_blocks, 256, 0, stream>>>(h, deg, b0, xn, n);

  // relation 1
  gemm_xw<<<gemm_blocks, 256, 0, stream>>>(x, W1, nullptr, h, n);
  scatter<<<sc_blocks, 256, 0, stream>>>(row, col, etype, h, deg + n, xd, E, 1);
  finalize<<<nf_blocks, 256, 0, stream>>>(h, deg + n, b1, xd, n);

  // self-loop linear into d_out
  gemm_xw<<<gemm_blocks, 256, 0, stream>>>(x, Wsl, bsl, xx, n);

  // gate + combine
  gemm_gate<<<gemm_blocks, 256, 0, stream>>>(xx, xn, xd, Wg, bg, logits, n);
  combine<<<(int)(((long long)n * 64 + 255) / 256), 256, 0, stream>>>(logits, xn, xd, xx, n);
}

// Round 3
// 341.870 us; speedup vs baseline: 3.7117x; 3.7117x over previous
//
#include <hip/hip_runtime.h>
#include <hip/hip_bf16.h>
#include <math.h>

// ---------------------------------------------------------------------------
// OGCNConv via CSR-gather (no feature atomics):
//   deg count (int) -> dinv -> prefix-scan buckets -> fill edge buckets
//   h_t = x@W_t (bf16) -> gather per dest node (+self-loop+bias)
//   xx = x@W_sl+b_sl -> fused gate GEMM (K=384) + softmax/cumsum/combine
// ---------------------------------------------------------------------------

__device__ inline float b2f(unsigned short u) {
  return __uint_as_float(((unsigned)u) << 16);
}
__device__ inline unsigned short f2bf(float f) {
  __hip_bfloat16 b = __float2bfloat16(f);
  return *reinterpret_cast<unsigned short*>(&b);
}

__global__ __launch_bounds__(256) void count_deg(const int* __restrict__ col,
                                                 const int* __restrict__ etype,
                                                 int* __restrict__ deg,  // [2n], zeroed
                                                 int E, int n) {
  int e = blockIdx.x * 256 + threadIdx.x;
  if (e >= E) return;
  atomicAdd(&deg[(size_t)etype[e] * n + col[e]], 1);
}

__global__ __launch_bounds__(256) void dinv_kernel(const int* __restrict__ deg,
                                                   float* __restrict__ dinv, int n2) {
  int i = blockIdx.x * 256 + threadIdx.x;
  if (i < n2) dinv[i] = rsqrtf((float)deg[i] + 1.0f);  // +1 self-loop
}

// ---- 3-kernel exclusive prefix scan over deg[0..n2) (2048 elems/block) ----
__global__ __launch_bounds__(256) void scan1(const int* __restrict__ d,
                                             int* __restrict__ partials, int n2) {
  int tid = threadIdx.x;
  int base = blockIdx.x * 2048 + tid * 8;
  int s = 0;
#pragma unroll
  for (int k = 0; k < 8; ++k) {
    int i = base + k;
    if (i < n2) s += d[i];
  }
  __shared__ int sb[256];
  sb[tid] = s;
  __syncthreads();
  for (int o = 128; o; o >>= 1) {
    if (tid < o) sb[tid] += sb[tid + o];
    __syncthreads();
  }
  if (tid == 0) partials[blockIdx.x] = sb[0];
}

__global__ __launch_bounds__(256) void scan2(int* __restrict__ partials, int nb) {
  int tid = threadIdx.x;
  int v = (tid < nb) ? partials[tid] : 0;
  __shared__ int sb[256];
  sb[tid] = v;
  __syncthreads();
  for (int o = 1; o < 256; o <<= 1) {
    int t = (tid >= o) ? sb[tid - o] : 0;
    __syncthreads();
    sb[tid] += t;
    __syncthreads();
  }
  if (tid < nb) partials[tid] = sb[tid] - v;  // exclusive
}

// writes row_start[i] (bucket start) and cursor[i]=start. cursor ALIASES deg
// (each thread reads its own 8 counts into regs before overwriting).
__global__ __launch_bounds__(256) void scan3(const int* __restrict__ partials,
                                             int* __restrict__ row_start,
                                             int* __restrict__ cursor, int n2) {
  int tid = threadIdx.x;
  int base = blockIdx.x * 2048 + tid * 8;
  int v[8];
  int s = 0;
#pragma unroll
  for (int k = 0; k < 8; ++k) {
    int i = base + k;
    v[k] = (i < n2) ? cursor[i] : 0;
    s += v[k];
  }
  __shared__ int sb[256];
  sb[tid] = s;
  __syncthreads();
  for (int o = 1; o < 256; o <<= 1) {
    int t = (tid >= o) ? sb[tid - o] : 0;
    __syncthreads();
    sb[tid] += t;
    __syncthreads();
  }
  int run = partials[blockIdx.x] + (sb[tid] - s);
#pragma unroll
  for (int k = 0; k < 8; ++k) {
    int i = base + k;
    if (i < n2) {
      row_start[i] = run;
      cursor[i] = run;
      run += v[k];
    }
  }
}

__global__ __launch_bounds__(256) void fill_buckets(const int* __restrict__ row,
                                                    const int* __restrict__ col,
                                                    const int* __restrict__ etype,
                                                    int* __restrict__ cursor,
                                                    int* __restrict__ ebuf, int E, int n) {
  int e = blockIdx.x * 256 + threadIdx.x;
  if (e >= E) return;
  int b = etype[e] * n + col[e];
  int pos = atomicAdd(&cursor[b], 1);
  ebuf[pos] = row[e];
}

// out = x @ W (+bias). 64-row tile/block, 8x4 register tile/thread.
// OUT_BF16=1 -> out is ushort* (bf16), else float*.
template <int OUT_BF16>
__global__ __launch_bounds__(256) void gemm_xw(const float* __restrict__ x,
                                               const float* __restrict__ W,
                                               const float* __restrict__ bias,
                                               void* __restrict__ outv, int n) {
  int row0 = blockIdx.x * 64;
  __shared__ float xs[64][128];  // 32 KB
  int tid = threadIdx.x;
  {
    const float4* xg = (const float4*)(x + (size_t)row0 * 128);
    float4* xl = (float4*)xs;
    int maxv = (n - row0) * 32;
#pragma unroll
    for (int i = 0; i < 8; ++i) {
      int idx = tid + i * 256;
      float4 v = {0.f, 0.f, 0.f, 0.f};
      if (idx < maxv) v = xg[idx];
      xl[idx] = v;
    }
  }
  __syncthreads();
  int c4 = tid & 31;
  int tr = tid >> 5;
  const float4* W4 = (const float4*)W;
  float acc[8][4] = {};
#pragma unroll 4
  for (int k = 0; k < 128; ++k) {
    float4 w = W4[k * 32 + c4];
#pragma unroll
    for (int i = 0; i < 8; ++i) {
      float a = xs[tr * 8 + i][k];
      acc[i][0] = fmaf(a, w.x, acc[i][0]);
      acc[i][1] = fmaf(a, w.y, acc[i][1]);
      acc[i][2] = fmaf(a, w.z, acc[i][2]);
      acc[i][3] = fmaf(a, w.w, acc[i][3]);
    }
  }
  float4 bv = {0.f, 0.f, 0.f, 0.f};
  if (bias) bv = ((const float4*)bias)[c4];
#pragma unroll
  for (int i = 0; i < 8; ++i) {
    int r = row0 + tr * 8 + i;
    if (r < n) {
      float o0 = acc[i][0] + bv.x, o1 = acc[i][1] + bv.y;
      float o2 = acc[i][2] + bv.z, o3 = acc[i][3] + bv.w;
      if (OUT_BF16) {
        ushort4 u;
        u.x = f2bf(o0);
        u.y = f2bf(o1);
        u.z = f2bf(o2);
        u.w = f2bf(o3);
        ((ushort4*)((unsigned short*)outv + (size_t)r * 128))[c4] = u;
      } else {
        float4 o = {o0, o1, o2, o3};
        ((float4*)((float*)outv + (size_t)r * 128))[c4] = o;
      }
    }
  }
}

// Per dest node: agg = sum_{e in bucket} h[src]*dinv[src]*dinv[node]
//                + h[node]*dinv[node]^2 + bias.    32 lanes/node, 4 feat/lane.
__global__ __launch_bounds__(256) void gather(const unsigned short* __restrict__ h,
                                              const int* __restrict__ ebuf,
                                              const int* __restrict__ row_startT,
                                              const int* __restrict__ cursorT,  // = end
                                              const float* __restrict__ dinvT,
                                              const float* __restrict__ bias,
                                              float* __restrict__ out, int n) {
  long long gid = (long long)blockIdx.x * 256 + threadIdx.x;
  int node = (int)(gid >> 5);
  if (node >= n) return;
  int f4 = (int)(gid & 31);
  float di = dinvT[node];
  const ushort4* hp4 = (const ushort4*)h;
  float4 bb = ((const float4*)bias)[f4];
  ushort4 sv = hp4[(size_t)node * 32 + f4];
  float sl = di * di;
  float4 acc;
  acc.x = fmaf(b2f(sv.x), sl, bb.x);
  acc.y = fmaf(b2f(sv.y), sl, bb.y);
  acc.z = fmaf(b2f(sv.z), sl, bb.z);
  acc.w = fmaf(b2f(sv.w), sl, bb.w);
  int s = row_startT[node];
  int e = cursorT[node];
  for (int j = s; j < e; ++j) {
    int r = ebuf[j];
    float nrm = dinvT[r] * di;
    ushort4 v = hp4[(size_t)r * 32 + f4];
    acc.x = fmaf(b2f(v.x), nrm, acc.x);
    acc.y = fmaf(b2f(v.y), nrm, acc.y);
    acc.z = fmaf(b2f(v.z), nrm, acc.z);
    acc.w = fmaf(b2f(v.w), nrm, acc.w);
  }
  ((float4*)out)[(size_t)node * 32 + f4] = acc;
}

// logits = [xx|xn|xd]@Wg + bg ; softmax; cumsum; out = rev(xd)*gat + xx + xn.
// xxout is d_out: read as xx input, overwritten with final output (own rows only).
__global__ __launch_bounds__(256) void gate_combine(const float* __restrict__ xn,
                                                    const float* __restrict__ xd,
                                                    const float* __restrict__ Wg,
                                                    const float* __restrict__ bg,
                                                    float* __restrict__ xxout, int n) {
  int row0 = blockIdx.x * 64;
  __shared__ float xs[64][128];
  int tid = threadIdx.x;
  int c4 = tid & 31;
  int tr = tid >> 5;
  float acc[8][4] = {};
  int maxv = (n - row0) * 32;
  for (int seg = 0; seg < 3; ++seg) {
    const float* A = (seg == 0) ? xxout : (seg == 1) ? xn : xd;
    const float4* xg = (const float4*)(A + (size_t)row0 * 128);
    float4* xl = (float4*)xs;
    __syncthreads();
#pragma unroll
    for (int i = 0; i < 8; ++i) {
      int idx = tid + i * 256;
      float4 v = {0.f, 0.f, 0.f, 0.f};
      if (idx < maxv) v = xg[idx];
      xl[idx] = v;
    }
    __syncthreads();
    const float4* W4 = (const float4*)(Wg + (size_t)seg * 128 * 128);
#pragma unroll 4
    for (int k = 0; k < 128; ++k) {
      float4 w = W4[k * 32 + c4];
#pragma unroll
      for (int i = 0; i < 8; ++i) {
        float a = xs[tr * 8 + i][k];
        acc[i][0] = fmaf(a, w.x, acc[i][0]);
        acc[i][1] = fmaf(a, w.y, acc[i][1]);
        acc[i][2] = fmaf(a, w.z, acc[i][2]);
        acc[i][3] = fmaf(a, w.w, acc[i][3]);
      }
    }
  }
  // stash logits (+bias) in LDS
  float4 bias = ((const float4*)bg)[c4];
  __syncthreads();
#pragma unroll
  for (int i = 0; i < 8; ++i) {
    int rr = tr * 8 + i;
    xs[rr][c4 * 4 + 0] = acc[i][0] + bias.x;
    xs[rr][c4 * 4 + 1] = acc[i][1] + bias.y;
    xs[rr][c4 * 4 + 2] = acc[i][2] + bias.z;
    xs[rr][c4 * 4 + 3] = acc[i][3] + bias.w;
  }
  __syncthreads();
  // per-row softmax + cumsum + combine; 4 waves x 16 rows
  int wv = tid >> 6;
  int lane = tid & 63;
  for (int q = 0; q < 16; ++q) {
    int rr = wv * 16 + q;
    int gr = row0 + rr;
    if (gr >= n) break;
    float a = xs[rr][lane];
    float b = xs[rr][64 + lane];
    float m = fmaxf(a, b);
#pragma unroll
    for (int o = 32; o; o >>= 1) m = fmaxf(m, __shfl_xor(m, o));
    a = __expf(a - m);
    b = __expf(b - m);
    float ssum = a + b;
#pragma unroll
    for (int o = 32; o; o >>= 1) ssum += __shfl_xor(ssum, o);
    float inv = 1.0f / ssum;
    a *= inv;
    b *= inv;
    float pa = a;
#pragma unroll
    for (int o = 1; o < 64; o <<= 1) {
      float t = __shfl_up(pa, o);
      if (lane >= o) pa += t;
    }
    float Sa = __shfl(pa, 63);
    float pb = b;
#pragma unroll
    for (int o = 1; o < 64; o <<= 1) {
      float t = __shfl_up(pb, o);
      if (lane >= o) pb += t;
    }
    size_t gbase = (size_t)gr * 128;
    float xx_a = xxout[gbase + lane];
    float xx_b = xxout[gbase + 64 + lane];
    float xn_a = xn[gbase + lane];
    float xn_b = xn[gbase + 64 + lane];
    float xd_ra = xd[gbase + 127 - lane];
    float xd_rb = xd[gbase + 63 - lane];
    xxout[gbase + lane] = fmaf(xd_ra, pa, xx_a + xn_a);
    xxout[gbase + 64 + lane] = fmaf(xd_rb, Sa + pb, xx_b + xn_b);
  }
}

extern "C" void kernel_launch(void* const* d_in, const int* in_sizes, int n_in,
                              void* d_out, int out_size, void* d_ws, size_t ws_size,
                              hipStream_t stream) {
  const float* x = (const float*)d_in[0];
  const int* eidx = (const int*)d_in[1];
  const int* etype = (const int*)d_in[2];
  const float* Wsl = (const float*)d_in[3];
  const float* bsl = (const float*)d_in[4];
  const float* W0 = (const float*)d_in[5];
  const float* b0 = (const float*)d_in[6];
  const float* W1 = (const float*)d_in[7];
  const float* b1 = (const float*)d_in[8];
  const float* Wg = (const float*)d_in[9];
  const float* bg = (const float*)d_in[10];
  int n = in_sizes[0] / 128;
  int E = in_sizes[2];
  const int* row = eidx;
  const int* col = eidx + E;
  int n2 = 2 * n;

  // ws layout (float units):
  // deg/cursor int[2n] | dinv f32[2n] | row_start int[2n] | partials int[256]
  // | ebuf int[E] | xn f32[128n] | xd f32[128n] | h bf16[128n]
  float* ws = (float*)d_ws;
  int* deg = (int*)ws;                    // aliased: cursor after scan3
  float* dinv = ws + (size_t)n2;
  int* row_start = (int*)(ws + 2 * (size_t)n2);
  int* partials = (int*)(ws + 3 * (size_t)n2);
  int* ebuf = partials + 256;
  float* xn = ws + 3 * (size_t)n2 + 256 + E;
  float* xd = xn + 128 * (size_t)n;
  unsigned short* h = (unsigned short*)(xd + 128 * (size_t)n);
  float* xx = (float*)d_out;

  hipMemsetAsync(deg, 0, (size_t)n2 * sizeof(int), stream);

  count_deg<<<(E + 255) / 256, 256, 0, stream>>>(col, etype, deg, E, n);
  dinv_kernel<<<(n2 + 255) / 256, 256, 0, stream>>>(deg, dinv, n2);

  int nb = (n2 + 2047) / 2048;
  scan1<<<nb, 256, 0, stream>>>(deg, partials, n2);
  scan2<<<1, 256, 0, stream>>>(partials, nb);
  scan3<<<nb, 256, 0, stream>>>(partials, row_start, deg, n2);
  fill_buckets<<<(E + 255) / 256, 256, 0, stream>>>(row, col, etype, deg, ebuf, E, n);

  int gemm_blocks = (n + 63) / 64;
  int ga_blocks = (int)(((long long)n * 32 + 255) / 256);

  // relation 0 -> xn
  gemm_xw<1><<<gemm_blocks, 256, 0, stream>>>(x, W0, nullptr, h, n);
  gather<<<ga_blocks, 256, 0, stream>>>(h, ebuf, row_start, deg, dinv, b0, xn, n);
  // relation 1 -> xd
  gemm_xw<1><<<gemm_blocks, 256, 0, stream>>>(x, W1, nullptr, h, n);
  gather<<<ga_blocks, 256, 0, stream>>>(h, ebuf, row_start + n, deg + n, dinv + n, b1, xd, n);
  // self-loop linear into d_out
  gemm_xw<0><<<gemm_blocks, 256, 0, stream>>>(x, Wsl, bsl, xx, n);
  // fused gate + combine
  gate_combine<<<gemm_blocks, 256, 0, stream>>>(xn, xd, Wg, bg, xx, n);
}

// Round 4
// 212.463 us; speedup vs baseline: 5.9724x; 1.6091x over previous
//
#include <hip/hip_runtime.h>
#include <hip/hip_bf16.h>
#include <math.h>

// ---------------------------------------------------------------------------
// OGCNConv, MFMA edition:
//   bucket build (count/scan/fill) -> fused 3-way GEMM x@[Wsl|W0|W1] (MFMA)
//   -> CSR gather per relation (bf16 out) -> fused gate GEMM (K=384, MFMA)
//      + in-register softmax/cumsum + combine.
// ---------------------------------------------------------------------------

typedef __attribute__((ext_vector_type(8))) short bf16x8;
typedef __attribute__((ext_vector_type(4))) float f32x4;
typedef __attribute__((ext_vector_type(8))) unsigned short ushort8;

__device__ inline float b2f(unsigned short u) {
  return __uint_as_float(((unsigned)u) << 16);
}
__device__ inline unsigned short f2bf(float f) {
  __hip_bfloat16 b = __float2bfloat16(f);
  return *reinterpret_cast<unsigned short*>(&b);
}

__global__ __launch_bounds__(256) void count_deg(const int* __restrict__ col,
                                                 const int* __restrict__ etype,
                                                 int* __restrict__ deg, int E, int n) {
  int e = blockIdx.x * 256 + threadIdx.x;
  if (e >= E) return;
  atomicAdd(&deg[(size_t)etype[e] * n + col[e]], 1);
}

__global__ __launch_bounds__(256) void dinv_kernel(const int* __restrict__ deg,
                                                   float* __restrict__ dinv, int n2) {
  int i = blockIdx.x * 256 + threadIdx.x;
  if (i < n2) dinv[i] = rsqrtf((float)deg[i] + 1.0f);
}

__global__ __launch_bounds__(256) void scan1(const int* __restrict__ d,
                                             int* __restrict__ partials, int n2) {
  int tid = threadIdx.x;
  int base = blockIdx.x * 2048 + tid * 8;
  int s = 0;
#pragma unroll
  for (int k = 0; k < 8; ++k) {
    int i = base + k;
    if (i < n2) s += d[i];
  }
  __shared__ int sb[256];
  sb[tid] = s;
  __syncthreads();
  for (int o = 128; o; o >>= 1) {
    if (tid < o) sb[tid] += sb[tid + o];
    __syncthreads();
  }
  if (tid == 0) partials[blockIdx.x] = sb[0];
}

__global__ __launch_bounds__(256) void scan2(int* __restrict__ partials, int nb) {
  int tid = threadIdx.x;
  int v = (tid < nb) ? partials[tid] : 0;
  __shared__ int sb[256];
  sb[tid] = v;
  __syncthreads();
  for (int o = 1; o < 256; o <<= 1) {
    int t = (tid >= o) ? sb[tid - o] : 0;
    __syncthreads();
    sb[tid] += t;
    __syncthreads();
  }
  if (tid < nb) partials[tid] = sb[tid] - v;
}

__global__ __launch_bounds__(256) void scan3(const int* __restrict__ partials,
                                             int* __restrict__ row_start,
                                             int* __restrict__ cursor, int n2) {
  int tid = threadIdx.x;
  int base = blockIdx.x * 2048 + tid * 8;
  int v[8];
  int s = 0;
#pragma unroll
  for (int k = 0; k < 8; ++k) {
    int i = base + k;
    v[k] = (i < n2) ? cursor[i] : 0;
    s += v[k];
  }
  __shared__ int sb[256];
  sb[tid] = s;
  __syncthreads();
  for (int o = 1; o < 256; o <<= 1) {
    int t = (tid >= o) ? sb[tid - o] : 0;
    __syncthreads();
    sb[tid] += t;
    __syncthreads();
  }
  int run = partials[blockIdx.x] + (sb[tid] - s);
#pragma unroll
  for (int k = 0; k < 8; ++k) {
    int i = base + k;
    if (i < n2) {
      row_start[i] = run;
      cursor[i] = run;
      run += v[k];
    }
  }
}

__global__ __launch_bounds__(256) void fill_buckets(const int* __restrict__ row,
                                                    const int* __restrict__ col,
                                                    const int* __restrict__ etype,
                                                    int* __restrict__ cursor,
                                                    int* __restrict__ ebuf, int E, int n) {
  int e = blockIdx.x * 256 + threadIdx.x;
  if (e >= E) return;
  int b = etype[e] * n + col[e];
  int pos = atomicAdd(&cursor[b], 1);
  ebuf[pos] = row[e];
}

// Pack W matrices into MFMA B-fragment order (bf16).
// Frag (ct,kf), lane l, elem j  <-  W[kf*32 + (l>>4)*8 + j][ct*16 + (l&15)]
__global__ __launch_bounds__(256) void pack_w(const float* __restrict__ Wsl,
                                              const float* __restrict__ W0,
                                              const float* __restrict__ W1,
                                              const float* __restrict__ Wg,
                                              unsigned short* __restrict__ Wp3,
                                              unsigned short* __restrict__ Wgp) {
  int tid = blockIdx.x * 256 + threadIdx.x;
  if (tid < 6144) {  // 3 mats, nct=8, nkf=4
    int z = tid / 2048, r = tid % 2048;
    int lane = r & 63, idx = r >> 6;  // idx = ct*4+kf
    int kf = idx & 3, ct = idx >> 2;
    const float* W = (z == 0) ? Wsl : (z == 1) ? W0 : W1;
    unsigned short* dst = Wp3 + (size_t)z * 16384 + (size_t)r * 8;
    int krow = kf * 32 + (lane >> 4) * 8;
    int ccol = ct * 16 + (lane & 15);
#pragma unroll
    for (int j = 0; j < 8; ++j) dst[j] = f2bf(W[(size_t)(krow + j) * 128 + ccol]);
  } else if (tid < 12288) {  // Wg: nct=8, nkf=12
    int r = tid - 6144;
    int lane = r & 63, idx = r >> 6;  // idx = ct*12+kf
    int kf = idx % 12, ct = idx / 12;
    unsigned short* dst = Wgp + (size_t)r * 8;
    int krow = kf * 32 + (lane >> 4) * 8;
    int ccol = ct * 16 + (lane & 15);
#pragma unroll
    for (int j = 0; j < 8; ++j) dst[j] = f2bf(Wg[(size_t)(krow + j) * 128 + ccol]);
  }
}

// Fused 3-way GEMM: [64 rows of x] @ {Wsl,W0,W1}. xx fp32 (+bsl), h0/h1 bf16.
__global__ __launch_bounds__(256) void gemm3_mfma(const float* __restrict__ x,
                                                  const unsigned short* __restrict__ Wp3,
                                                  const float* __restrict__ bsl,
                                                  float* __restrict__ xx,
                                                  unsigned short* __restrict__ h0,
                                                  unsigned short* __restrict__ h1, int n) {
  int row0 = blockIdx.x * 64;
  __shared__ unsigned short xs[64 * 136];  // 64 rows, stride 136 (pad) bf16
  int tid = threadIdx.x;
  {
    const float4* xg = (const float4*)(x + (size_t)row0 * 128);
    int maxv = (n - row0) * 32;
#pragma unroll
    for (int i = 0; i < 8; ++i) {
      int idx = tid + i * 256;
      float4 v = {0.f, 0.f, 0.f, 0.f};
      if (idx < maxv) v = xg[idx];
      int row = idx >> 5, c4 = idx & 31;
      ushort4 u;
      u.x = f2bf(v.x);
      u.y = f2bf(v.y);
      u.z = f2bf(v.z);
      u.w = f2bf(v.w);
      *(ushort4*)&xs[row * 136 + c4 * 4] = u;
    }
  }
  __syncthreads();
  int w = tid >> 6;        // wave 0..3 -> rows w*16..w*16+15
  int l = tid & 63;
  int q = l >> 4;          // quarter
  int c = l & 15;          // col-within-tile / A-row-within-tile
  bf16x8 af[4];
#pragma unroll
  for (int kf = 0; kf < 4; ++kf)
    af[kf] = *(const bf16x8*)&xs[(w * 16 + c) * 136 + kf * 32 + q * 8];

  int gr0 = row0 + w * 16 + q * 4;
#pragma unroll
  for (int z = 0; z < 3; ++z) {
    const bf16x8* Bp = (const bf16x8*)(Wp3 + (size_t)z * 16384);
#pragma unroll
    for (int ct = 0; ct < 8; ++ct) {
      f32x4 acc = {0.f, 0.f, 0.f, 0.f};
#pragma unroll
      for (int kf = 0; kf < 4; ++kf)
        acc = __builtin_amdgcn_mfma_f32_16x16x32_bf16(af[kf], Bp[(ct * 4 + kf) * 64 + l], acc, 0, 0, 0);
      int fc = ct * 16 + c;
      if (z == 0) {
        float bias = bsl[fc];
#pragma unroll
        for (int i = 0; i < 4; ++i) {
          int gr = gr0 + i;
          if (gr < n) xx[(size_t)gr * 128 + fc] = acc[i] + bias;
        }
      } else {
        unsigned short* h = (z == 1) ? h0 : h1;
#pragma unroll
        for (int i = 0; i < 4; ++i) {
          int gr = gr0 + i;
          if (gr < n) h[(size_t)gr * 128 + fc] = f2bf(acc[i]);
        }
      }
    }
  }
}

// CSR gather, bf16 h in, bf16 out. 32 lanes/node, 4 feats/lane.
__global__ __launch_bounds__(256) void gather(const unsigned short* __restrict__ h,
                                              const int* __restrict__ ebuf,
                                              const int* __restrict__ row_startT,
                                              const int* __restrict__ cursorT,
                                              const float* __restrict__ dinvT,
                                              const float* __restrict__ bias,
                                              unsigned short* __restrict__ out, int n) {
  long long gid = (long long)blockIdx.x * 256 + threadIdx.x;
  int node = (int)(gid >> 5);
  if (node >= n) return;
  int f4 = (int)(gid & 31);
  float di = dinvT[node];
  const ushort4* hp4 = (const ushort4*)h;
  float4 bb = ((const float4*)bias)[f4];
  ushort4 sv = hp4[(size_t)node * 32 + f4];
  float sl = di * di;
  float4 acc;
  acc.x = fmaf(b2f(sv.x), sl, bb.x);
  acc.y = fmaf(b2f(sv.y), sl, bb.y);
  acc.z = fmaf(b2f(sv.z), sl, bb.z);
  acc.w = fmaf(b2f(sv.w), sl, bb.w);
  int s = row_startT[node];
  int e = cursorT[node];
  for (int j = s; j < e; ++j) {
    int r = ebuf[j];
    float nrm = dinvT[r] * di;
    ushort4 v = hp4[(size_t)r * 32 + f4];
    acc.x = fmaf(b2f(v.x), nrm, acc.x);
    acc.y = fmaf(b2f(v.y), nrm, acc.y);
    acc.z = fmaf(b2f(v.z), nrm, acc.z);
    acc.w = fmaf(b2f(v.w), nrm, acc.w);
  }
  ushort4 u;
  u.x = f2bf(acc.x);
  u.y = f2bf(acc.y);
  u.z = f2bf(acc.z);
  u.w = f2bf(acc.w);
  ((ushort4*)out)[(size_t)node * 32 + f4] = u;
}

// Gate GEMM (K=384, MFMA) + softmax + cumsum + combine, all fused.
// xxg = d_out: read fp32 xx, overwritten with final output (own rows only).
__global__ __launch_bounds__(256) void gate_combine(const unsigned short* __restrict__ xn,
                                                    const unsigned short* __restrict__ xd,
                                                    const unsigned short* __restrict__ Wgp,
                                                    const float* __restrict__ bg,
                                                    float* __restrict__ xxg, int n) {
  int row0 = blockIdx.x * 64;
  __shared__ unsigned short ys[64 * 392];  // cols: 0..127 xx | 128..255 xn | 256..383 xd
  int tid = threadIdx.x;
  {  // stage xx (fp32 -> bf16)
    const float4* xg = (const float4*)(xxg + (size_t)row0 * 128);
    int maxv = (n - row0) * 32;
#pragma unroll
    for (int i = 0; i < 8; ++i) {
      int idx = tid + i * 256;
      float4 v = {0.f, 0.f, 0.f, 0.f};
      if (idx < maxv) v = xg[idx];
      int row = idx >> 5, c4 = idx & 31;
      ushort4 u;
      u.x = f2bf(v.x);
      u.y = f2bf(v.y);
      u.z = f2bf(v.z);
      u.w = f2bf(v.w);
      *(ushort4*)&ys[row * 392 + c4 * 4] = u;
    }
  }
  {  // stage xn, xd (bf16 copy)
    int maxv8 = (n - row0) * 16;
    const ushort8* ng = (const ushort8*)(xn + (size_t)row0 * 128);
    const ushort8* dg = (const ushort8*)(xd + (size_t)row0 * 128);
#pragma unroll
    for (int i = 0; i < 4; ++i) {
      int idx = tid + i * 256;
      int row = idx >> 4, c8 = idx & 15;
      ushort8 a = {0, 0, 0, 0, 0, 0, 0, 0}, b = a;
      if (idx < maxv8) {
        a = ng[idx];
        b = dg[idx];
      }
      *(ushort8*)&ys[row * 392 + 128 + c8 * 8] = a;
      *(ushort8*)&ys[row * 392 + 256 + c8 * 8] = b;
    }
  }
  __syncthreads();
  int w = tid >> 6;
  int l = tid & 63;
  int q = l >> 4;
  int c = l & 15;
  bf16x8 af[12];
#pragma unroll
  for (int kf = 0; kf < 12; ++kf)
    af[kf] = *(const bf16x8*)&ys[(w * 16 + c) * 392 + kf * 32 + q * 8];
  const bf16x8* Bp = (const bf16x8*)Wgp;
  f32x4 acc[8];
#pragma unroll
  for (int ct = 0; ct < 8; ++ct) acc[ct] = (f32x4){0.f, 0.f, 0.f, 0.f};
#pragma unroll
  for (int kf = 0; kf < 12; ++kf) {
    bf16x8 a = af[kf];
#pragma unroll
    for (int ct = 0; ct < 8; ++ct)
      acc[ct] = __builtin_amdgcn_mfma_f32_16x16x32_bf16(a, Bp[(ct * 12 + kf) * 64 + l], acc[ct], 0, 0, 0);
  }
  // + bias
#pragma unroll
  for (int ct = 0; ct < 8; ++ct) {
    float bgv = bg[ct * 16 + c];
#pragma unroll
    for (int i = 0; i < 4; ++i) acc[ct][i] += bgv;
  }
  // per-row (row = w*16 + q*4 + i) softmax + cumsum + combine
  int rrb = w * 16 + q * 4;
#pragma unroll
  for (int i = 0; i < 4; ++i) {
    float m = acc[0][i];
#pragma unroll
    for (int ct = 1; ct < 8; ++ct) m = fmaxf(m, acc[ct][i]);
#pragma unroll
    for (int o = 1; o < 16; o <<= 1) m = fmaxf(m, __shfl_xor(m, o));
    float e[8];
    float s = 0.f;
#pragma unroll
    for (int ct = 0; ct < 8; ++ct) {
      e[ct] = __expf(acc[ct][i] - m);
      s += e[ct];
    }
#pragma unroll
    for (int o = 1; o < 16; o <<= 1) s += __shfl_xor(s, o);
    float inv = 1.0f / s;
    int rr = rrb + i;
    int gr = row0 + rr;
    float run = 0.f;
#pragma unroll
    for (int ct = 0; ct < 8; ++ct) {
      float p = e[ct];
#pragma unroll
      for (int o = 1; o < 16; o <<= 1) {
        float t = __shfl_up(p, o);
        if (c >= o) p += t;
      }
      float T = __shfl(p, q * 16 + 15);
      float gat = (run + p) * inv;
      run += T;
      int f = ct * 16 + c;
      float xxv = b2f(ys[rr * 392 + f]);
      float xnv = b2f(ys[rr * 392 + 128 + f]);
      float xdv = b2f(ys[rr * 392 + 256 + 127 - f]);
      if (gr < n) xxg[(size_t)gr * 128 + f] = fmaf(xdv, gat, xxv + xnv);
    }
  }
}

extern "C" void kernel_launch(void* const* d_in, const int* in_sizes, int n_in,
                              void* d_out, int out_size, void* d_ws, size_t ws_size,
                              hipStream_t stream) {
  const float* x = (const float*)d_in[0];
  const int* eidx = (const int*)d_in[1];
  const int* etype = (const int*)d_in[2];
  const float* Wsl = (const float*)d_in[3];
  const float* bsl = (const float*)d_in[4];
  const float* W0 = (const float*)d_in[5];
  const float* b0 = (const float*)d_in[6];
  const float* W1 = (const float*)d_in[7];
  const float* b1 = (const float*)d_in[8];
  const float* Wg = (const float*)d_in[9];
  const float* bg = (const float*)d_in[10];
  int n = in_sizes[0] / 128;
  int E = in_sizes[2];
  const int* row = eidx;
  const int* col = eidx + E;
  int n2 = 2 * n;

  char* w = (char*)d_ws;
  int* deg = (int*)w;             w += (size_t)n2 * 4;   // aliased as cursor
  float* dinv = (float*)w;        w += (size_t)n2 * 4;
  int* row_start = (int*)w;       w += (size_t)n2 * 4;
  int* partials = (int*)w;        w += 1024;
  int* ebuf = (int*)w;            w += (size_t)E * 4;
  unsigned short* Wp3 = (unsigned short*)w;  w += 3 * 128 * 128 * 2;
  unsigned short* Wgp = (unsigned short*)w;  w += 384 * 128 * 2;
  unsigned short* xn = (unsigned short*)w;   w += (size_t)n * 128 * 2;
  unsigned short* xd = (unsigned short*)w;   w += (size_t)n * 128 * 2;
  unsigned short* h0 = (unsigned short*)w;   w += (size_t)n * 128 * 2;
  unsigned short* h1 = (unsigned short*)w;
  float* xx = (float*)d_out;

  hipMemsetAsync(deg, 0, (size_t)n2 * 4, stream);

  pack_w<<<48, 256, 0, stream>>>(Wsl, W0, W1, Wg, Wp3, Wgp);
  count_deg<<<(E + 255) / 256, 256, 0, stream>>>(col, etype, deg, E, n);
  dinv_kernel<<<(n2 + 255) / 256, 256, 0, stream>>>(deg, dinv, n2);

  int nb = (n2 + 2047) / 2048;
  scan1<<<nb, 256, 0, stream>>>(deg, partials, n2);
  scan2<<<1, 256, 0, stream>>>(partials, nb);
  scan3<<<nb, 256, 0, stream>>>(partials, row_start, deg, n2);
  fill_buckets<<<(E + 255) / 256, 256, 0, stream>>>(row, col, etype, deg, ebuf, E, n);

  int gemm_blocks = (n + 63) / 64;
  int ga_blocks = (int)(((long long)n * 32 + 255) / 256);

  gemm3_mfma<<<gemm_blocks, 256, 0, stream>>>(x, Wp3, bsl, xx, h0, h1, n);
  gather<<<ga_blocks, 256, 0, stream>>>(h0, ebuf, row_start, deg, dinv, b0, xn, n);
  gather<<<ga_blocks, 256, 0, stream>>>(h1, ebuf, row_start + n, deg + n, dinv + n, b1, xd, n);
  gate_combine<<<gemm_blocks, 256, 0, stream>>>(xn, xd, Wgp, bg, xx, n);
}

// Round 5
// 204.745 us; speedup vs baseline: 6.1975x; 1.0377x over previous
//
#include <hip/hip_runtime.h>
#include <hip/hip_bf16.h>
#include <math.h>

// ---------------------------------------------------------------------------
// OGCNConv, MFMA edition v2:
//   bucket build -> fused 3-way GEMM x@[Wsl|W0|W1] (MFMA, all-bf16 out)
//   -> merged CSR gather (both relations, gridDim.y=2)
//   -> gate GEMM (K=384, MFMA, 1-wave/16-row blocks, zero LDS)
//      + in-register softmax/cumsum + combine (writes d_out).
// ---------------------------------------------------------------------------

typedef __attribute__((ext_vector_type(8))) short bf16x8;
typedef __attribute__((ext_vector_type(4))) float f32x4;
typedef __attribute__((ext_vector_type(8))) unsigned short ushort8;

__device__ inline float b2f(unsigned short u) {
  return __uint_as_float(((unsigned)u) << 16);
}
__device__ inline unsigned short f2bf(float f) {
  __hip_bfloat16 b = __float2bfloat16(f);
  return *reinterpret_cast<unsigned short*>(&b);
}

__global__ __launch_bounds__(256) void count_deg(const int* __restrict__ col,
                                                 const int* __restrict__ etype,
                                                 int* __restrict__ deg, int E, int n) {
  int e = blockIdx.x * 256 + threadIdx.x;
  if (e >= E) return;
  atomicAdd(&deg[(size_t)etype[e] * n + col[e]], 1);
}

__global__ __launch_bounds__(256) void dinv_kernel(const int* __restrict__ deg,
                                                   float* __restrict__ dinv, int n2) {
  int i = blockIdx.x * 256 + threadIdx.x;
  if (i < n2) dinv[i] = rsqrtf((float)deg[i] + 1.0f);
}

__global__ __launch_bounds__(256) void scan1(const int* __restrict__ d,
                                             int* __restrict__ partials, int n2) {
  int tid = threadIdx.x;
  int base = blockIdx.x * 2048 + tid * 8;
  int s = 0;
#pragma unroll
  for (int k = 0; k < 8; ++k) {
    int i = base + k;
    if (i < n2) s += d[i];
  }
  __shared__ int sb[256];
  sb[tid] = s;
  __syncthreads();
  for (int o = 128; o; o >>= 1) {
    if (tid < o) sb[tid] += sb[tid + o];
    __syncthreads();
  }
  if (tid == 0) partials[blockIdx.x] = sb[0];
}

__global__ __launch_bounds__(256) void scan2(int* __restrict__ partials, int nb) {
  int tid = threadIdx.x;
  int v = (tid < nb) ? partials[tid] : 0;
  __shared__ int sb[256];
  sb[tid] = v;
  __syncthreads();
  for (int o = 1; o < 256; o <<= 1) {
    int t = (tid >= o) ? sb[tid - o] : 0;
    __syncthreads();
    sb[tid] += t;
    __syncthreads();
  }
  if (tid < nb) partials[tid] = sb[tid] - v;
}

__global__ __launch_bounds__(256) void scan3(const int* __restrict__ partials,
                                             int* __restrict__ row_start,
                                             int* __restrict__ cursor, int n2) {
  int tid = threadIdx.x;
  int base = blockIdx.x * 2048 + tid * 8;
  int v[8];
  int s = 0;
#pragma unroll
  for (int k = 0; k < 8; ++k) {
    int i = base + k;
    v[k] = (i < n2) ? cursor[i] : 0;
    s += v[k];
  }
  __shared__ int sb[256];
  sb[tid] = s;
  __syncthreads();
  for (int o = 1; o < 256; o <<= 1) {
    int t = (tid >= o) ? sb[tid - o] : 0;
    __syncthreads();
    sb[tid] += t;
    __syncthreads();
  }
  int run = partials[blockIdx.x] + (sb[tid] - s);
#pragma unroll
  for (int k = 0; k < 8; ++k) {
    int i = base + k;
    if (i < n2) {
      row_start[i] = run;
      cursor[i] = run;
      run += v[k];
    }
  }
}

__global__ __launch_bounds__(256) void fill_buckets(const int* __restrict__ row,
                                                    const int* __restrict__ col,
                                                    const int* __restrict__ etype,
                                                    int* __restrict__ cursor,
                                                    int* __restrict__ ebuf, int E, int n) {
  int e = blockIdx.x * 256 + threadIdx.x;
  if (e >= E) return;
  int b = etype[e] * n + col[e];
  int pos = atomicAdd(&cursor[b], 1);
  ebuf[pos] = row[e];
}

// Pack W matrices into MFMA B-fragment order (bf16).
// Frag (ct,kf), lane l, elem j  <-  W[kf*32 + (l>>4)*8 + j][ct*16 + (l&15)]
__global__ __launch_bounds__(256) void pack_w(const float* __restrict__ Wsl,
                                              const float* __restrict__ W0,
                                              const float* __restrict__ W1,
                                              const float* __restrict__ Wg,
                                              unsigned short* __restrict__ Wp3,
                                              unsigned short* __restrict__ Wgp) {
  int tid = blockIdx.x * 256 + threadIdx.x;
  if (tid < 6144) {  // 3 mats, nct=8, nkf=4
    int z = tid / 2048, r = tid % 2048;
    int lane = r & 63, idx = r >> 6;  // idx = ct*4+kf
    int kf = idx & 3, ct = idx >> 2;
    const float* W = (z == 0) ? Wsl : (z == 1) ? W0 : W1;
    unsigned short* dst = Wp3 + (size_t)z * 16384 + (size_t)r * 8;
    int krow = kf * 32 + (lane >> 4) * 8;
    int ccol = ct * 16 + (lane & 15);
#pragma unroll
    for (int j = 0; j < 8; ++j) dst[j] = f2bf(W[(size_t)(krow + j) * 128 + ccol]);
  } else if (tid < 12288) {  // Wg: nct=8, nkf=12
    int r = tid - 6144;
    int lane = r & 63, idx = r >> 6;  // idx = ct*12+kf
    int kf = idx % 12, ct = idx / 12;
    unsigned short* dst = Wgp + (size_t)r * 8;
    int krow = kf * 32 + (lane >> 4) * 8;
    int ccol = ct * 16 + (lane & 15);
#pragma unroll
    for (int j = 0; j < 8; ++j) dst[j] = f2bf(Wg[(size_t)(krow + j) * 128 + ccol]);
  }
}

// Fused 3-way GEMM: [64 rows of x] @ {Wsl,W0,W1} -> hx,h0,h1 (bf16).
__global__ __launch_bounds__(256) void gemm3_mfma(const float* __restrict__ x,
                                                  const unsigned short* __restrict__ Wp3,
                                                  const float* __restrict__ bsl,
                                                  unsigned short* __restrict__ hx,
                                                  unsigned short* __restrict__ h0,
                                                  unsigned short* __restrict__ h1, int n) {
  int row0 = blockIdx.x * 64;
  __shared__ unsigned short xs[64 * 136];  // 64 rows, stride 136 (pad) bf16
  int tid = threadIdx.x;
  {
    const float4* xg = (const float4*)(x + (size_t)row0 * 128);
    int maxv = (n - row0) * 32;
#pragma unroll
    for (int i = 0; i < 8; ++i) {
      int idx = tid + i * 256;
      float4 v = {0.f, 0.f, 0.f, 0.f};
      if (idx < maxv) v = xg[idx];
      int row = idx >> 5, c4 = idx & 31;
      ushort4 u;
      u.x = f2bf(v.x);
      u.y = f2bf(v.y);
      u.z = f2bf(v.z);
      u.w = f2bf(v.w);
      *(ushort4*)&xs[row * 136 + c4 * 4] = u;
    }
  }
  __syncthreads();
  int w = tid >> 6;        // wave 0..3 -> rows w*16..w*16+15
  int l = tid & 63;
  int q = l >> 4;          // quarter
  int c = l & 15;          // col-within-tile / A-row-within-tile
  bf16x8 af[4];
#pragma unroll
  for (int kf = 0; kf < 4; ++kf)
    af[kf] = *(const bf16x8*)&xs[(w * 16 + c) * 136 + kf * 32 + q * 8];

  int gr0 = row0 + w * 16 + q * 4;
#pragma unroll
  for (int z = 0; z < 3; ++z) {
    const bf16x8* Bp = (const bf16x8*)(Wp3 + (size_t)z * 16384);
    unsigned short* h = (z == 0) ? hx : (z == 1) ? h0 : h1;
#pragma unroll
    for (int ct = 0; ct < 8; ++ct) {
      f32x4 acc = {0.f, 0.f, 0.f, 0.f};
#pragma unroll
      for (int kf = 0; kf < 4; ++kf)
        acc = __builtin_amdgcn_mfma_f32_16x16x32_bf16(af[kf], Bp[(ct * 4 + kf) * 64 + l], acc, 0, 0, 0);
      int fc = ct * 16 + c;
      float bias = (z == 0) ? bsl[fc] : 0.f;
#pragma unroll
      for (int i = 0; i < 4; ++i) {
        int gr = gr0 + i;
        if (gr < n) h[(size_t)gr * 128 + fc] = f2bf(acc[i] + bias);
      }
    }
  }
}

// Merged CSR gather (both relations via blockIdx.y). 32 lanes/node, 4 feats/lane.
__global__ __launch_bounds__(256) void gather2(const unsigned short* __restrict__ h0,
                                               const unsigned short* __restrict__ h1,
                                               const int* __restrict__ ebuf,
                                               const int* __restrict__ row_start,
                                               const int* __restrict__ cursor,
                                               const float* __restrict__ dinv,
                                               const float* __restrict__ b0,
                                               const float* __restrict__ b1,
                                               unsigned short* __restrict__ xn,
                                               unsigned short* __restrict__ xd, int n) {
  int t = blockIdx.y;
  long long gid = (long long)blockIdx.x * 256 + threadIdx.x;
  int node = (int)(gid >> 5);
  if (node >= n) return;
  int f4 = (int)(gid & 31);
  const unsigned short* h = t ? h1 : h0;
  const float* bias = t ? b1 : b0;
  unsigned short* out = t ? xd : xn;
  const int* rs = row_start + (size_t)t * n;
  const int* cu = cursor + (size_t)t * n;
  const float* dv = dinv + (size_t)t * n;

  float di = dv[node];
  const ushort4* hp4 = (const ushort4*)h;
  float4 bb = ((const float4*)bias)[f4];
  ushort4 sv = hp4[(size_t)node * 32 + f4];
  float sl = di * di;
  float4 acc;
  acc.x = fmaf(b2f(sv.x), sl, bb.x);
  acc.y = fmaf(b2f(sv.y), sl, bb.y);
  acc.z = fmaf(b2f(sv.z), sl, bb.z);
  acc.w = fmaf(b2f(sv.w), sl, bb.w);
  int s = rs[node];
  int e = cu[node];
  for (int j = s; j < e; ++j) {
    int r = ebuf[j];
    float nrm = dv[r] * di;
    ushort4 v = hp4[(size_t)r * 32 + f4];
    acc.x = fmaf(b2f(v.x), nrm, acc.x);
    acc.y = fmaf(b2f(v.y), nrm, acc.y);
    acc.z = fmaf(b2f(v.z), nrm, acc.z);
    acc.w = fmaf(b2f(v.w), nrm, acc.w);
  }
  ushort4 u;
  u.x = f2bf(acc.x);
  u.y = f2bf(acc.y);
  u.z = f2bf(acc.z);
  u.w = f2bf(acc.w);
  ((ushort4*)out)[(size_t)node * 32 + f4] = u;
}

// Gate GEMM (K=384, MFMA) + softmax + cumsum + combine. 1 wave / 16 rows, no LDS.
__global__ __launch_bounds__(64) void gate_combine(const unsigned short* __restrict__ hx,
                                                   const unsigned short* __restrict__ xn,
                                                   const unsigned short* __restrict__ xd,
                                                   const unsigned short* __restrict__ Wgp,
                                                   const float* __restrict__ bg,
                                                   float* __restrict__ out, int n) {
  int row0 = blockIdx.x * 16;
  int l = threadIdx.x;
  int q = l >> 4;
  int c = l & 15;
  int ar = row0 + c;
  if (ar >= n) ar = n - 1;  // clamp; outputs are guarded
  // A-fragments straight from global (bf16, L2-resident)
  bf16x8 af[12];
  {
    const unsigned short* p0 = hx + (size_t)ar * 128 + q * 8;
    const unsigned short* p1 = xn + (size_t)ar * 128 + q * 8;
    const unsigned short* p2 = xd + (size_t)ar * 128 + q * 8;
#pragma unroll
    for (int k = 0; k < 4; ++k) {
      af[k] = *(const bf16x8*)(p0 + k * 32);
      af[4 + k] = *(const bf16x8*)(p1 + k * 32);
      af[8 + k] = *(const bf16x8*)(p2 + k * 32);
    }
  }
  const bf16x8* Bp = (const bf16x8*)Wgp;
  f32x4 acc[8];
#pragma unroll
  for (int ct = 0; ct < 8; ++ct) acc[ct] = (f32x4){0.f, 0.f, 0.f, 0.f};
#pragma unroll
  for (int kf = 0; kf < 12; ++kf) {
    bf16x8 a = af[kf];
#pragma unroll
    for (int ct = 0; ct < 8; ++ct)
      acc[ct] = __builtin_amdgcn_mfma_f32_16x16x32_bf16(a, Bp[(ct * 12 + kf) * 64 + l], acc[ct], 0, 0, 0);
  }
#pragma unroll
  for (int ct = 0; ct < 8; ++ct) {
    float bgv = bg[ct * 16 + c];
#pragma unroll
    for (int i = 0; i < 4; ++i) acc[ct][i] += bgv;
  }
  // per-row (row = q*4 + i) softmax + cumsum + combine
#pragma unroll
  for (int i = 0; i < 4; ++i) {
    float m = acc[0][i];
#pragma unroll
    for (int ct = 1; ct < 8; ++ct) m = fmaxf(m, acc[ct][i]);
#pragma unroll
    for (int o = 1; o < 16; o <<= 1) m = fmaxf(m, __shfl_xor(m, o));
    float e[8];
    float s = 0.f;
#pragma unroll
    for (int ct = 0; ct < 8; ++ct) {
      e[ct] = __expf(acc[ct][i] - m);
      s += e[ct];
    }
#pragma unroll
    for (int o = 1; o < 16; o <<= 1) s += __shfl_xor(s, o);
    float inv = 1.0f / s;
    int gr = row0 + q * 4 + i;
    float run = 0.f;
#pragma unroll
    for (int ct = 0; ct < 8; ++ct) {
      float p = e[ct];
#pragma unroll
      for (int o = 1; o < 16; o <<= 1) {
        float t = __shfl_up(p, o);
        if (c >= o) p += t;
      }
      float T = __shfl(p, q * 16 + 15);
      float gat = (run + p) * inv;
      run += T;
      int f = ct * 16 + c;
      if (gr < n) {
        size_t gb = (size_t)gr * 128;
        float xxv = b2f(hx[gb + f]);
        float xnv = b2f(xn[gb + f]);
        float xdv = b2f(xd[gb + 127 - f]);
        out[gb + f] = fmaf(xdv, gat, xxv + xnv);
      }
    }
  }
}

extern "C" void kernel_launch(void* const* d_in, const int* in_sizes, int n_in,
                              void* d_out, int out_size, void* d_ws, size_t ws_size,
                              hipStream_t stream) {
  const float* x = (const float*)d_in[0];
  const int* eidx = (const int*)d_in[1];
  const int* etype = (const int*)d_in[2];
  const float* Wsl = (const float*)d_in[3];
  const float* bsl = (const float*)d_in[4];
  const float* W0 = (const float*)d_in[5];
  const float* b0 = (const float*)d_in[6];
  const float* W1 = (const float*)d_in[7];
  const float* b1 = (const float*)d_in[8];
  const float* Wg = (const float*)d_in[9];
  const float* bg = (const float*)d_in[10];
  int n = in_sizes[0] / 128;
  int E = in_sizes[2];
  const int* row = eidx;
  const int* col = eidx + E;
  int n2 = 2 * n;

  char* w = (char*)d_ws;
  int* deg = (int*)w;             w += (size_t)n2 * 4;   // aliased as cursor
  float* dinv = (float*)w;        w += (size_t)n2 * 4;
  int* row_start = (int*)w;       w += (size_t)n2 * 4;
  int* partials = (int*)w;        w += 1024;
  int* ebuf = (int*)w;            w += (size_t)E * 4;
  unsigned short* Wp3 = (unsigned short*)w;  w += 3 * 128 * 128 * 2;
  unsigned short* Wgp = (unsigned short*)w;  w += 384 * 128 * 2;
  unsigned short* hx = (unsigned short*)w;   w += (size_t)n * 128 * 2;
  unsigned short* h0 = (unsigned short*)w;   w += (size_t)n * 128 * 2;
  unsigned short* h1 = (unsigned short*)w;   w += (size_t)n * 128 * 2;
  unsigned short* xn = (unsigned short*)w;   w += (size_t)n * 128 * 2;
  unsigned short* xd = (unsigned short*)w;
  float* out = (float*)d_out;

  hipMemsetAsync(deg, 0, (size_t)n2 * 4, stream);

  pack_w<<<48, 256, 0, stream>>>(Wsl, W0, W1, Wg, Wp3, Wgp);
  count_deg<<<(E + 255) / 256, 256, 0, stream>>>(col, etype, deg, E, n);
  dinv_kernel<<<(n2 + 255) / 256, 256, 0, stream>>>(deg, dinv, n2);

  int nb = (n2 + 2047) / 2048;
  scan1<<<nb, 256, 0, stream>>>(deg, partials, n2);
  scan2<<<1, 256, 0, stream>>>(partials, nb);
  scan3<<<nb, 256, 0, stream>>>(partials, row_start, deg, n2);
  fill_buckets<<<(E + 255) / 256, 256, 0, stream>>>(row, col, etype, deg, ebuf, E, n);

  int gemm_blocks = (n + 63) / 64;
  int ga_blocks = (int)(((long long)n * 32 + 255) / 256);

  gemm3_mfma<<<gemm_blocks, 256, 0, stream>>>(x, Wp3, bsl, hx, h0, h1, n);
  gather2<<<dim3(ga_blocks, 2), 256, 0, stream>>>(h0, h1, ebuf, row_start, deg, dinv,
                                                  b0, b1, xn, xd, n);
  gate_combine<<<(n + 15) / 16, 64, 0, stream>>>(hx, xn, xd, Wgp, bg, out, n);
}

// Round 6
// 171.380 us; speedup vs baseline: 7.4041x; 1.1947x over previous
//
#include <hip/hip_runtime.h>
#include <hip/hip_bf16.h>
#include <math.h>

// ---------------------------------------------------------------------------
// OGCNConv, MFMA edition v3:
//   bucket build (edge records carry precomputed norm) -> fused 3-way GEMM
//   x@[Wsl|W0|W1] (MFMA, bf16 out) -> merged CSR gather (16 lanes/node,
//   unroll-2) -> gate GEMM (K=384, MFMA, 1-wave blocks) + softmax/cumsum.
// ---------------------------------------------------------------------------

typedef __attribute__((ext_vector_type(8))) short bf16x8;
typedef __attribute__((ext_vector_type(4))) float f32x4;
typedef __attribute__((ext_vector_type(8))) unsigned short ushort8;

__device__ inline float b2f(unsigned short u) {
  return __uint_as_float(((unsigned)u) << 16);
}
__device__ inline unsigned short f2bf(float f) {
  __hip_bfloat16 b = __float2bfloat16(f);
  return *reinterpret_cast<unsigned short*>(&b);
}

// --- fused: blocks [0,48) pack W into MFMA B-fragment order; rest count deg.
__global__ __launch_bounds__(256) void pack_count(const float* __restrict__ Wsl,
                                                  const float* __restrict__ W0,
                                                  const float* __restrict__ W1,
                                                  const float* __restrict__ Wg,
                                                  unsigned short* __restrict__ Wp3,
                                                  unsigned short* __restrict__ Wgp,
                                                  const int* __restrict__ col,
                                                  const int* __restrict__ etype,
                                                  int* __restrict__ deg, int E, int n) {
  if (blockIdx.x < 48) {
    int tid = blockIdx.x * 256 + threadIdx.x;
    if (tid < 6144) {  // 3 mats, nct=8, nkf=4
      int z = tid / 2048, r = tid % 2048;
      int lane = r & 63, idx = r >> 6;  // idx = ct*4+kf
      int kf = idx & 3, ct = idx >> 2;
      const float* W = (z == 0) ? Wsl : (z == 1) ? W0 : W1;
      unsigned short* dst = Wp3 + (size_t)z * 16384 + (size_t)r * 8;
      int krow = kf * 32 + (lane >> 4) * 8;
      int ccol = ct * 16 + (lane & 15);
#pragma unroll
      for (int j = 0; j < 8; ++j) dst[j] = f2bf(W[(size_t)(krow + j) * 128 + ccol]);
    } else {  // Wg: nct=8, nkf=12
      int r = tid - 6144;
      int lane = r & 63, idx = r >> 6;  // idx = ct*12+kf
      int kf = idx % 12, ct = idx / 12;
      unsigned short* dst = Wgp + (size_t)r * 8;
      int krow = kf * 32 + (lane >> 4) * 8;
      int ccol = ct * 16 + (lane & 15);
#pragma unroll
      for (int j = 0; j < 8; ++j) dst[j] = f2bf(Wg[(size_t)(krow + j) * 128 + ccol]);
    }
  } else {
    int e = (blockIdx.x - 48) * 256 + threadIdx.x;
    if (e >= E) return;
    atomicAdd(&deg[(size_t)etype[e] * n + col[e]], 1);
  }
}

// --- fused: blocks [0,nb) do scan1 partials; rest compute dinv.
__global__ __launch_bounds__(256) void dinv_scan1(const int* __restrict__ deg,
                                                  float* __restrict__ dinv,
                                                  int* __restrict__ partials,
                                                  int n2, int nb) {
  int tid = threadIdx.x;
  if ((int)blockIdx.x < nb) {
    int base = blockIdx.x * 2048 + tid * 8;
    int s = 0;
#pragma unroll
    for (int k = 0; k < 8; ++k) {
      int i = base + k;
      if (i < n2) s += deg[i];
    }
    __shared__ int sb[256];
    sb[tid] = s;
    __syncthreads();
    for (int o = 128; o; o >>= 1) {
      if (tid < o) sb[tid] += sb[tid + o];
      __syncthreads();
    }
    if (tid == 0) partials[blockIdx.x] = sb[0];
  } else {
    int i = (blockIdx.x - nb) * 256 + tid;
    if (i < n2) dinv[i] = rsqrtf((float)deg[i] + 1.0f);
  }
}

__global__ __launch_bounds__(256) void scan2(int* __restrict__ partials, int nb) {
  int tid = threadIdx.x;
  int v = (tid < nb) ? partials[tid] : 0;
  __shared__ int sb[256];
  sb[tid] = v;
  __syncthreads();
  for (int o = 1; o < 256; o <<= 1) {
    int t = (tid >= o) ? sb[tid - o] : 0;
    __syncthreads();
    sb[tid] += t;
    __syncthreads();
  }
  if (tid < nb) partials[tid] = sb[tid] - v;
}

__global__ __launch_bounds__(256) void scan3(const int* __restrict__ partials,
                                             int* __restrict__ row_start,
                                             int* __restrict__ cursor, int n2) {
  int tid = threadIdx.x;
  int base = blockIdx.x * 2048 + tid * 8;
  int v[8];
  int s = 0;
#pragma unroll
  for (int k = 0; k < 8; ++k) {
    int i = base + k;
    v[k] = (i < n2) ? cursor[i] : 0;
    s += v[k];
  }
  __shared__ int sb[256];
  sb[tid] = s;
  __syncthreads();
  for (int o = 1; o < 256; o <<= 1) {
    int t = (tid >= o) ? sb[tid - o] : 0;
    __syncthreads();
    sb[tid] += t;
    __syncthreads();
  }
  int run = partials[blockIdx.x] + (sb[tid] - s);
#pragma unroll
  for (int k = 0; k < 8; ++k) {
    int i = base + k;
    if (i < n2) {
      row_start[i] = run;
      cursor[i] = run;
      run += v[k];
    }
  }
}

// Edge record: {src row, precomputed nrm = dinv[src]*dinv[dst]}.
__global__ __launch_bounds__(256) void fill_buckets(const int* __restrict__ row,
                                                    const int* __restrict__ col,
                                                    const int* __restrict__ etype,
                                                    const float* __restrict__ dinv,
                                                    int* __restrict__ cursor,
                                                    int2* __restrict__ ebuf, int E, int n) {
  int e = blockIdx.x * 256 + threadIdx.x;
  if (e >= E) return;
  int r = row[e], c = col[e], t = etype[e];
  int b = t * n + c;
  float nrm = dinv[t * n + r] * dinv[b];
  int pos = atomicAdd(&cursor[b], 1);
  ebuf[pos] = make_int2(r, __float_as_int(nrm));
}

// Fused 3-way GEMM: [64 rows of x] @ {Wsl,W0,W1} -> hx,h0,h1 (bf16).
__global__ __launch_bounds__(256) void gemm3_mfma(const float* __restrict__ x,
                                                  const unsigned short* __restrict__ Wp3,
                                                  const float* __restrict__ bsl,
                                                  unsigned short* __restrict__ hx,
                                                  unsigned short* __restrict__ h0,
                                                  unsigned short* __restrict__ h1, int n) {
  int row0 = blockIdx.x * 64;
  __shared__ unsigned short xs[64 * 136];
  int tid = threadIdx.x;
  {
    const float4* xg = (const float4*)(x + (size_t)row0 * 128);
    int maxv = (n - row0) * 32;
#pragma unroll
    for (int i = 0; i < 8; ++i) {
      int idx = tid + i * 256;
      float4 v = {0.f, 0.f, 0.f, 0.f};
      if (idx < maxv) v = xg[idx];
      int row = idx >> 5, c4 = idx & 31;
      ushort4 u;
      u.x = f2bf(v.x);
      u.y = f2bf(v.y);
      u.z = f2bf(v.z);
      u.w = f2bf(v.w);
      *(ushort4*)&xs[row * 136 + c4 * 4] = u;
    }
  }
  __syncthreads();
  int w = tid >> 6;
  int l = tid & 63;
  int q = l >> 4;
  int c = l & 15;
  bf16x8 af[4];
#pragma unroll
  for (int kf = 0; kf < 4; ++kf)
    af[kf] = *(const bf16x8*)&xs[(w * 16 + c) * 136 + kf * 32 + q * 8];

  int gr0 = row0 + w * 16 + q * 4;
#pragma unroll
  for (int z = 0; z < 3; ++z) {
    const bf16x8* Bp = (const bf16x8*)(Wp3 + (size_t)z * 16384);
    unsigned short* h = (z == 0) ? hx : (z == 1) ? h0 : h1;
#pragma unroll
    for (int ct = 0; ct < 8; ++ct) {
      f32x4 acc = {0.f, 0.f, 0.f, 0.f};
#pragma unroll
      for (int kf = 0; kf < 4; ++kf)
        acc = __builtin_amdgcn_mfma_f32_16x16x32_bf16(af[kf], Bp[(ct * 4 + kf) * 64 + l], acc, 0, 0, 0);
      int fc = ct * 16 + c;
      float bias = (z == 0) ? bsl[fc] : 0.f;
#pragma unroll
      for (int i = 0; i < 4; ++i) {
        int gr = gr0 + i;
        if (gr < n) h[(size_t)gr * 128 + fc] = f2bf(acc[i] + bias);
      }
    }
  }
}

// Merged CSR gather, 16 lanes/node (ushort8/lane), unroll-2, precomputed nrm.
__global__ __launch_bounds__(256) void gather2(const unsigned short* __restrict__ h0,
                                               const unsigned short* __restrict__ h1,
                                               const int2* __restrict__ ebuf,
                                               const int* __restrict__ row_start,
                                               const int* __restrict__ cursor,
                                               const float* __restrict__ dinv,
                                               const float* __restrict__ b0,
                                               const float* __restrict__ b1,
                                               unsigned short* __restrict__ xn,
                                               unsigned short* __restrict__ xd, int n) {
  int t = blockIdx.y;
  long long gid = (long long)blockIdx.x * 256 + threadIdx.x;
  int node = (int)(gid >> 4);
  if (node >= n) return;
  int f8 = (int)(gid & 15);
  const unsigned short* h = t ? h1 : h0;
  const float* bias = t ? b1 : b0;
  unsigned short* out = t ? xd : xn;
  const int* rs = row_start + (size_t)t * n;
  const int* cu = cursor + (size_t)t * n;
  float di = dinv[(size_t)t * n + node];

  const ushort8* hp8 = (const ushort8*)h;
  float acc[8];
  {
    ushort8 sv = hp8[(size_t)node * 16 + f8];
    float sl = di * di;
#pragma unroll
    for (int k = 0; k < 8; ++k) acc[k] = fmaf(b2f(sv[k]), sl, bias[f8 * 8 + k]);
  }
  int s = rs[node];
  int e = cu[node];
  int j = s;
  float acc2[8] = {0.f, 0.f, 0.f, 0.f, 0.f, 0.f, 0.f, 0.f};
  for (; j + 1 < e; j += 2) {
    int2 r0 = ebuf[j];
    int2 r1 = ebuf[j + 1];
    ushort8 v0 = hp8[(size_t)r0.x * 16 + f8];
    ushort8 v1 = hp8[(size_t)r1.x * 16 + f8];
    float n0 = __int_as_float(r0.y);
    float n1 = __int_as_float(r1.y);
#pragma unroll
    for (int k = 0; k < 8; ++k) acc[k] = fmaf(b2f(v0[k]), n0, acc[k]);
#pragma unroll
    for (int k = 0; k < 8; ++k) acc2[k] = fmaf(b2f(v1[k]), n1, acc2[k]);
  }
  if (j < e) {
    int2 r0 = ebuf[j];
    ushort8 v0 = hp8[(size_t)r0.x * 16 + f8];
    float n0 = __int_as_float(r0.y);
#pragma unroll
    for (int k = 0; k < 8; ++k) acc[k] = fmaf(b2f(v0[k]), n0, acc[k]);
  }
  ushort8 u;
#pragma unroll
  for (int k = 0; k < 8; ++k) u[k] = f2bf(acc[k] + acc2[k]);
  ((ushort8*)out)[(size_t)node * 16 + f8] = u;
}

// Gate GEMM (K=384, MFMA) + softmax + cumsum + combine. 1 wave / 16 rows, no LDS.
__global__ __launch_bounds__(64) void gate_combine(const unsigned short* __restrict__ hx,
                                                   const unsigned short* __restrict__ xn,
                                                   const unsigned short* __restrict__ xd,
                                                   const unsigned short* __restrict__ Wgp,
                                                   const float* __restrict__ bg,
                                                   float* __restrict__ out, int n) {
  int row0 = blockIdx.x * 16;
  int l = threadIdx.x;
  int q = l >> 4;
  int c = l & 15;
  int ar = row0 + c;
  if (ar >= n) ar = n - 1;  // clamp; outputs are guarded
  bf16x8 af[12];
  {
    const unsigned short* p0 = hx + (size_t)ar * 128 + q * 8;
    const unsigned short* p1 = xn + (size_t)ar * 128 + q * 8;
    const unsigned short* p2 = xd + (size_t)ar * 128 + q * 8;
#pragma unroll
    for (int k = 0; k < 4; ++k) {
      af[k] = *(const bf16x8*)(p0 + k * 32);
      af[4 + k] = *(const bf16x8*)(p1 + k * 32);
      af[8 + k] = *(const bf16x8*)(p2 + k * 32);
    }
  }
  const bf16x8* Bp = (const bf16x8*)Wgp;
  f32x4 acc[8];
#pragma unroll
  for (int ct = 0; ct < 8; ++ct) acc[ct] = (f32x4){0.f, 0.f, 0.f, 0.f};
#pragma unroll
  for (int kf = 0; kf < 12; ++kf) {
    bf16x8 a = af[kf];
#pragma unroll
    for (int ct = 0; ct < 8; ++ct)
      acc[ct] = __builtin_amdgcn_mfma_f32_16x16x32_bf16(a, Bp[(ct * 12 + kf) * 64 + l], acc[ct], 0, 0, 0);
  }
#pragma unroll
  for (int ct = 0; ct < 8; ++ct) {
    float bgv = bg[ct * 16 + c];
#pragma unroll
    for (int i = 0; i < 4; ++i) acc[ct][i] += bgv;
  }
#pragma unroll
  for (int i = 0; i < 4; ++i) {
    float m = acc[0][i];
#pragma unroll
    for (int ct = 1; ct < 8; ++ct) m = fmaxf(m, acc[ct][i]);
#pragma unroll
    for (int o = 1; o < 16; o <<= 1) m = fmaxf(m, __shfl_xor(m, o));
    float e[8];
    float s = 0.f;
#pragma unroll
    for (int ct = 0; ct < 8; ++ct) {
      e[ct] = __expf(acc[ct][i] - m);
      s += e[ct];
    }
#pragma unroll
    for (int o = 1; o < 16; o <<= 1) s += __shfl_xor(s, o);
    float inv = 1.0f / s;
    int gr = row0 + q * 4 + i;
    float run = 0.f;
#pragma unroll
    for (int ct = 0; ct < 8; ++ct) {
      float p = e[ct];
#pragma unroll
      for (int o = 1; o < 16; o <<= 1) {
        float t = __shfl_up(p, o);
        if (c >= o) p += t;
      }
      float T = __shfl(p, q * 16 + 15);
      float gat = (run + p) * inv;
      run += T;
      int f = ct * 16 + c;
      if (gr < n) {
        size_t gb = (size_t)gr * 128;
        float xxv = b2f(hx[gb + f]);
        float xnv = b2f(xn[gb + f]);
        float xdv = b2f(xd[gb + 127 - f]);
        out[gb + f] = fmaf(xdv, gat, xxv + xnv);
      }
    }
  }
}

extern "C" void kernel_launch(void* const* d_in, const int* in_sizes, int n_in,
                              void* d_out, int out_size, void* d_ws, size_t ws_size,
                              hipStream_t stream) {
  const float* x = (const float*)d_in[0];
  const int* eidx = (const int*)d_in[1];
  const int* etype = (const int*)d_in[2];
  const float* Wsl = (const float*)d_in[3];
  const float* bsl = (const float*)d_in[4];
  const float* W0 = (const float*)d_in[5];
  const float* b0 = (const float*)d_in[6];
  const float* W1 = (const float*)d_in[7];
  const float* b1 = (const float*)d_in[8];
  const float* Wg = (const float*)d_in[9];
  const float* bg = (const float*)d_in[10];
  int n = in_sizes[0] / 128;
  int E = in_sizes[2];
  const int* row = eidx;
  const int* col = eidx + E;
  int n2 = 2 * n;

  char* w = (char*)d_ws;
  int* deg = (int*)w;             w += (size_t)n2 * 4;   // aliased as cursor
  float* dinv = (float*)w;        w += (size_t)n2 * 4;
  int* row_start = (int*)w;       w += (size_t)n2 * 4;
  int* partials = (int*)w;        w += 1024;
  int2* ebuf = (int2*)w;          w += (size_t)E * 8;
  unsigned short* Wp3 = (unsigned short*)w;  w += 3 * 128 * 128 * 2;
  unsigned short* Wgp = (unsigned short*)w;  w += 384 * 128 * 2;
  unsigned short* hx = (unsigned short*)w;   w += (size_t)n * 128 * 2;
  unsigned short* h0 = (unsigned short*)w;   w += (size_t)n * 128 * 2;
  unsigned short* h1 = (unsigned short*)w;   w += (size_t)n * 128 * 2;
  unsigned short* xn = (unsigned short*)w;   w += (size_t)n * 128 * 2;
  unsigned short* xd = (unsigned short*)w;
  float* out = (float*)d_out;

  hipMemsetAsync(deg, 0, (size_t)n2 * 4, stream);

  int cd_blocks = (E + 255) / 256;
  pack_count<<<48 + cd_blocks, 256, 0, stream>>>(Wsl, W0, W1, Wg, Wp3, Wgp,
                                                 col, etype, deg, E, n);
  int nb = (n2 + 2047) / 2048;
  dinv_scan1<<<nb + (n2 + 255) / 256, 256, 0, stream>>>(deg, dinv, partials, n2, nb);
  scan2<<<1, 256, 0, stream>>>(partials, nb);
  scan3<<<nb, 256, 0, stream>>>(partials, row_start, deg, n2);
  fill_buckets<<<cd_blocks, 256, 0, stream>>>(row, col, etype, dinv, deg, ebuf, E, n);

  int gemm_blocks = (n + 63) / 64;
  gemm3_mfma<<<gemm_blocks, 256, 0, stream>>>(x, Wp3, bsl, hx, h0, h1, n);

  int ga_blocks = (int)(((long long)n * 16 + 255) / 256);
  gather2<<<dim3(ga_blocks, 2), 256, 0, stream>>>(h0, h1, ebuf, row_start, deg, dinv,
                                                  b0, b1, xn, xd, n);
  gate_combine<<<(n + 15) / 16, 64, 0, stream>>>(hx, xn, xd, Wgp, bg, out, n);
}

// Round 7
// 145.681 us; speedup vs baseline: 8.7102x; 1.1764x over previous
//
#include <hip/hip_runtime.h>
#include <hip/hip_bf16.h>
#include <hip/hip_fp16.h>
#include <math.h>

// ---------------------------------------------------------------------------
// OGCNConv, MFMA edition v4:
//   pack_count (W pack + deg count + edge rank) -> dinv_scan1 -> scan3b
//   (inlined top-level scan) -> gemm3_fill (fused MFMA GEMM + bucket fill,
//   4B records {row:u16, nrm:fp16}, no atomics) -> gather2 (8 lanes/node,
//   unroll-2) -> gate_combine (K=384 MFMA + softmax/cumsum, 1-wave blocks).
// ---------------------------------------------------------------------------

typedef __attribute__((ext_vector_type(8))) short bf16x8;
typedef __attribute__((ext_vector_type(4))) float f32x4;
typedef __attribute__((ext_vector_type(8))) unsigned short ushort8;

__device__ inline float b2f(unsigned short u) {
  return __uint_as_float(((unsigned)u) << 16);
}
__device__ inline unsigned short f2bf(float f) {
  __hip_bfloat16 b = __float2bfloat16(f);
  return *reinterpret_cast<unsigned short*>(&b);
}

// --- blocks [0,48): pack W to MFMA B-fragment order; rest: deg count + rank.
__global__ __launch_bounds__(256) void pack_count(const float* __restrict__ Wsl,
                                                  const float* __restrict__ W0,
                                                  const float* __restrict__ W1,
                                                  const float* __restrict__ Wg,
                                                  unsigned short* __restrict__ Wp3,
                                                  unsigned short* __restrict__ Wgp,
                                                  const int* __restrict__ col,
                                                  const int* __restrict__ etype,
                                                  int* __restrict__ deg,
                                                  int* __restrict__ erank, int E, int n) {
  if (blockIdx.x < 48) {
    int tid = blockIdx.x * 256 + threadIdx.x;
    if (tid < 6144) {  // 3 mats, nct=8, nkf=4
      int z = tid / 2048, r = tid % 2048;
      int lane = r & 63, idx = r >> 6;
      int kf = idx & 3, ct = idx >> 2;
      const float* W = (z == 0) ? Wsl : (z == 1) ? W0 : W1;
      unsigned short* dst = Wp3 + (size_t)z * 16384 + (size_t)r * 8;
      int krow = kf * 32 + (lane >> 4) * 8;
      int ccol = ct * 16 + (lane & 15);
#pragma unroll
      for (int j = 0; j < 8; ++j) dst[j] = f2bf(W[(size_t)(krow + j) * 128 + ccol]);
    } else {  // Wg: nct=8, nkf=12
      int r = tid - 6144;
      int lane = r & 63, idx = r >> 6;
      int kf = idx % 12, ct = idx / 12;
      unsigned short* dst = Wgp + (size_t)r * 8;
      int krow = kf * 32 + (lane >> 4) * 8;
      int ccol = ct * 16 + (lane & 15);
#pragma unroll
      for (int j = 0; j < 8; ++j) dst[j] = f2bf(Wg[(size_t)(krow + j) * 128 + ccol]);
    }
  } else {
    int e = (blockIdx.x - 48) * 256 + threadIdx.x;
    if (e >= E) return;
    int rk = atomicAdd(&deg[(size_t)etype[e] * n + col[e]], 1);
    erank[e] = rk;
  }
}

// --- blocks [0,nb): scan1 partials; rest: dinv.
__global__ __launch_bounds__(256) void dinv_scan1(const int* __restrict__ deg,
                                                  float* __restrict__ dinv,
                                                  int* __restrict__ partials,
                                                  int n2, int nb) {
  int tid = threadIdx.x;
  if ((int)blockIdx.x < nb) {
    int base = blockIdx.x * 2048 + tid * 8;
    int s = 0;
#pragma unroll
    for (int k = 0; k < 8; ++k) {
      int i = base + k;
      if (i < n2) s += deg[i];
    }
    __shared__ int sb[256];
    sb[tid] = s;
    __syncthreads();
    for (int o = 128; o; o >>= 1) {
      if (tid < o) sb[tid] += sb[tid + o];
      __syncthreads();
    }
    if (tid == 0) partials[blockIdx.x] = sb[0];
  } else {
    int i = (blockIdx.x - nb) * 256 + tid;
    if (i < n2) dinv[i] = rsqrtf((float)deg[i] + 1.0f);
  }
}

// Exclusive scan: every block redundantly scans partials (nb<=256) in LDS,
// then scans its own 2048 deg values. Writes row_start only (deg preserved).
__global__ __launch_bounds__(256) void scan3b(const int* __restrict__ partials,
                                              const int* __restrict__ deg,
                                              int* __restrict__ row_start, int n2, int nb) {
  __shared__ int sb[256];
  __shared__ int ex[256];
  int tid = threadIdx.x;
  int pv = (tid < nb) ? partials[tid] : 0;
  sb[tid] = pv;
  __syncthreads();
  for (int o = 1; o < 256; o <<= 1) {
    int t = (tid >= o) ? sb[tid - o] : 0;
    __syncthreads();
    sb[tid] += t;
    __syncthreads();
  }
  ex[tid] = sb[tid] - pv;
  __syncthreads();
  int base = ex[blockIdx.x];
  __syncthreads();

  int bstart = blockIdx.x * 2048 + tid * 8;
  int v[8];
  int s = 0;
#pragma unroll
  for (int k = 0; k < 8; ++k) {
    int i = bstart + k;
    v[k] = (i < n2) ? deg[i] : 0;
    s += v[k];
  }
  sb[tid] = s;
  __syncthreads();
  for (int o = 1; o < 256; o <<= 1) {
    int t = (tid >= o) ? sb[tid - o] : 0;
    __syncthreads();
    sb[tid] += t;
    __syncthreads();
  }
  int run = base + (sb[tid] - s);
#pragma unroll
  for (int k = 0; k < 8; ++k) {
    int i = bstart + k;
    if (i < n2) {
      row_start[i] = run;
      run += v[k];
    }
  }
}

// Fused: blocks [0,gb) = 3-way MFMA GEMM; blocks [gb, gb+fb) = bucket fill.
__global__ __launch_bounds__(256) void gemm3_fill(
    const float* __restrict__ x, const unsigned short* __restrict__ Wp3,
    const float* __restrict__ bsl, unsigned short* __restrict__ hx,
    unsigned short* __restrict__ h0, unsigned short* __restrict__ h1,
    const int* __restrict__ row, const int* __restrict__ col,
    const int* __restrict__ etype, const int* __restrict__ erank,
    const int* __restrict__ row_start, const float* __restrict__ dinv,
    unsigned int* __restrict__ ebuf, int n, int E, int gb) {
  __shared__ unsigned short xs[64 * 136];
  int tid = threadIdx.x;
  if ((int)blockIdx.x >= gb) {  // ---- fill branch ----
    int e = (blockIdx.x - gb) * 256 + tid;
    if (e >= E) return;
    int r = row[e], c = col[e], t = etype[e];
    int b = t * n + c;
    float nrm = dinv[t * n + r] * dinv[b];
    int pos = row_start[b] + erank[e];
    unsigned int rec = (unsigned int)(r & 0xFFFF) |
                       ((unsigned int)__half_as_ushort(__float2half_rn(nrm)) << 16);
    ebuf[pos] = rec;
    return;
  }
  // ---- GEMM branch ----
  int row0 = blockIdx.x * 64;
  {
    const float4* xg = (const float4*)(x + (size_t)row0 * 128);
    int maxv = (n - row0) * 32;
#pragma unroll
    for (int i = 0; i < 8; ++i) {
      int idx = tid + i * 256;
      float4 v = {0.f, 0.f, 0.f, 0.f};
      if (idx < maxv) v = xg[idx];
      int rr = idx >> 5, c4 = idx & 31;
      ushort4 u;
      u.x = f2bf(v.x);
      u.y = f2bf(v.y);
      u.z = f2bf(v.z);
      u.w = f2bf(v.w);
      *(ushort4*)&xs[rr * 136 + c4 * 4] = u;
    }
  }
  __syncthreads();
  int w = tid >> 6;
  int l = tid & 63;
  int q = l >> 4;
  int c = l & 15;
  bf16x8 af[4];
#pragma unroll
  for (int kf = 0; kf < 4; ++kf)
    af[kf] = *(const bf16x8*)&xs[(w * 16 + c) * 136 + kf * 32 + q * 8];

  int gr0 = row0 + w * 16 + q * 4;
#pragma unroll
  for (int z = 0; z < 3; ++z) {
    const bf16x8* Bp = (const bf16x8*)(Wp3 + (size_t)z * 16384);
    unsigned short* h = (z == 0) ? hx : (z == 1) ? h0 : h1;
#pragma unroll
    for (int ct = 0; ct < 8; ++ct) {
      f32x4 acc = {0.f, 0.f, 0.f, 0.f};
#pragma unroll
      for (int kf = 0; kf < 4; ++kf)
        acc = __builtin_amdgcn_mfma_f32_16x16x32_bf16(af[kf], Bp[(ct * 4 + kf) * 64 + l], acc, 0, 0, 0);
      int fc = ct * 16 + c;
      float bias = (z == 0) ? bsl[fc] : 0.f;
#pragma unroll
      for (int i = 0; i < 4; ++i) {
        int gr = gr0 + i;
        if (gr < n) h[(size_t)gr * 128 + fc] = f2bf(acc[i] + bias);
      }
    }
  }
}

// Merged CSR gather: 8 lanes/node (2x ushort8 per lane), unroll-2.
__global__ __launch_bounds__(256) void gather2(const unsigned short* __restrict__ h0,
                                               const unsigned short* __restrict__ h1,
                                               const unsigned int* __restrict__ ebuf,
                                               const int* __restrict__ row_start,
                                               const int* __restrict__ deg,
                                               const float* __restrict__ dinv,
                                               const float* __restrict__ b0,
                                               const float* __restrict__ b1,
                                               unsigned short* __restrict__ xn,
                                               unsigned short* __restrict__ xd, int n) {
  int t = blockIdx.y;
  long long gid = (long long)blockIdx.x * 256 + threadIdx.x;
  int node = (int)(gid >> 3);
  if (node >= n) return;
  int sub = (int)(gid & 7);
  const ushort8* hp8 = (const ushort8*)(t ? h1 : h0);
  const float* bias = t ? b1 : b0;
  unsigned short* out = t ? xd : xn;
  const int* rs = row_start + (size_t)t * n;
  const int* dg = deg + (size_t)t * n;
  float di = dinv[(size_t)t * n + node];

  float accA[8], accB[8];
  float acc2A[8] = {0, 0, 0, 0, 0, 0, 0, 0}, acc2B[8] = {0, 0, 0, 0, 0, 0, 0, 0};
  {
    ushort8 sa = hp8[(size_t)node * 16 + sub * 2];
    ushort8 sbv = hp8[(size_t)node * 16 + sub * 2 + 1];
    float sl = di * di;
#pragma unroll
    for (int k = 0; k < 8; ++k) {
      accA[k] = fmaf(b2f(sa[k]), sl, bias[sub * 16 + k]);
      accB[k] = fmaf(b2f(sbv[k]), sl, bias[sub * 16 + 8 + k]);
    }
  }
  int s = rs[node];
  int e = s + dg[node];
  int j = s;
  for (; j + 1 < e; j += 2) {
    unsigned int r0 = ebuf[j], r1 = ebuf[j + 1];
    int i0 = (int)(r0 & 0xFFFFu), i1 = (int)(r1 & 0xFFFFu);
    float n0 = __half2float(__ushort_as_half((unsigned short)(r0 >> 16)));
    float n1 = __half2float(__ushort_as_half((unsigned short)(r1 >> 16)));
    ushort8 v0a = hp8[(size_t)i0 * 16 + sub * 2];
    ushort8 v0b = hp8[(size_t)i0 * 16 + sub * 2 + 1];
    ushort8 v1a = hp8[(size_t)i1 * 16 + sub * 2];
    ushort8 v1b = hp8[(size_t)i1 * 16 + sub * 2 + 1];
#pragma unroll
    for (int k = 0; k < 8; ++k) {
      accA[k] = fmaf(b2f(v0a[k]), n0, accA[k]);
      accB[k] = fmaf(b2f(v0b[k]), n0, accB[k]);
      acc2A[k] = fmaf(b2f(v1a[k]), n1, acc2A[k]);
      acc2B[k] = fmaf(b2f(v1b[k]), n1, acc2B[k]);
    }
  }
  if (j < e) {
    unsigned int r0 = ebuf[j];
    int i0 = (int)(r0 & 0xFFFFu);
    float n0 = __half2float(__ushort_as_half((unsigned short)(r0 >> 16)));
    ushort8 v0a = hp8[(size_t)i0 * 16 + sub * 2];
    ushort8 v0b = hp8[(size_t)i0 * 16 + sub * 2 + 1];
#pragma unroll
    for (int k = 0; k < 8; ++k) {
      accA[k] = fmaf(b2f(v0a[k]), n0, accA[k]);
      accB[k] = fmaf(b2f(v0b[k]), n0, accB[k]);
    }
  }
  ushort8 ua, ub;
#pragma unroll
  for (int k = 0; k < 8; ++k) {
    ua[k] = f2bf(accA[k] + acc2A[k]);
    ub[k] = f2bf(accB[k] + acc2B[k]);
  }
  ((ushort8*)out)[(size_t)node * 16 + sub * 2] = ua;
  ((ushort8*)out)[(size_t)node * 16 + sub * 2 + 1] = ub;
}

// Gate GEMM (K=384, MFMA) + softmax + cumsum + combine. 1 wave / 16 rows, no LDS.
__global__ __launch_bounds__(64) void gate_combine(const unsigned short* __restrict__ hx,
                                                   const unsigned short* __restrict__ xn,
                                                   const unsigned short* __restrict__ xd,
                                                   const unsigned short* __restrict__ Wgp,
                                                   const float* __restrict__ bg,
                                                   float* __restrict__ out, int n) {
  int row0 = blockIdx.x * 16;
  int l = threadIdx.x;
  int q = l >> 4;
  int c = l & 15;
  int ar = row0 + c;
  if (ar >= n) ar = n - 1;  // clamp; outputs are guarded
  bf16x8 af[12];
  {
    const unsigned short* p0 = hx + (size_t)ar * 128 + q * 8;
    const unsigned short* p1 = xn + (size_t)ar * 128 + q * 8;
    const unsigned short* p2 = xd + (size_t)ar * 128 + q * 8;
#pragma unroll
    for (int k = 0; k < 4; ++k) {
      af[k] = *(const bf16x8*)(p0 + k * 32);
      af[4 + k] = *(const bf16x8*)(p1 + k * 32);
      af[8 + k] = *(const bf16x8*)(p2 + k * 32);
    }
  }
  const bf16x8* Bp = (const bf16x8*)Wgp;
  f32x4 acc[8];
#pragma unroll
  for (int ct = 0; ct < 8; ++ct) acc[ct] = (f32x4){0.f, 0.f, 0.f, 0.f};
#pragma unroll
  for (int kf = 0; kf < 12; ++kf) {
    bf16x8 a = af[kf];
#pragma unroll
    for (int ct = 0; ct < 8; ++ct)
      acc[ct] = __builtin_amdgcn_mfma_f32_16x16x32_bf16(a, Bp[(ct * 12 + kf) * 64 + l], acc[ct], 0, 0, 0);
  }
#pragma unroll
  for (int ct = 0; ct < 8; ++ct) {
    float bgv = bg[ct * 16 + c];
#pragma unroll
    for (int i = 0; i < 4; ++i) acc[ct][i] += bgv;
  }
#pragma unroll
  for (int i = 0; i < 4; ++i) {
    float m = acc[0][i];
#pragma unroll
    for (int ct = 1; ct < 8; ++ct) m = fmaxf(m, acc[ct][i]);
#pragma unroll
    for (int o = 1; o < 16; o <<= 1) m = fmaxf(m, __shfl_xor(m, o));
    float e[8];
    float s = 0.f;
#pragma unroll
    for (int ct = 0; ct < 8; ++ct) {
      e[ct] = __expf(acc[ct][i] - m);
      s += e[ct];
    }
#pragma unroll
    for (int o = 1; o < 16; o <<= 1) s += __shfl_xor(s, o);
    float inv = 1.0f / s;
    int gr = row0 + q * 4 + i;
    float run = 0.f;
#pragma unroll
    for (int ct = 0; ct < 8; ++ct) {
      float p = e[ct];
#pragma unroll
      for (int o = 1; o < 16; o <<= 1) {
        float t = __shfl_up(p, o);
        if (c >= o) p += t;
      }
      float T = __shfl(p, q * 16 + 15);
      float gat = (run + p) * inv;
      run += T;
      int f = ct * 16 + c;
      if (gr < n) {
        size_t gb = (size_t)gr * 128;
        float xxv = b2f(hx[gb + f]);
        float xnv = b2f(xn[gb + f]);
        float xdv = b2f(xd[gb + 127 - f]);
        out[gb + f] = fmaf(xdv, gat, xxv + xnv);
      }
    }
  }
}

extern "C" void kernel_launch(void* const* d_in, const int* in_sizes, int n_in,
                              void* d_out, int out_size, void* d_ws, size_t ws_size,
                              hipStream_t stream) {
  const float* x = (const float*)d_in[0];
  const int* eidx = (const int*)d_in[1];
  const int* etype = (const int*)d_in[2];
  const float* Wsl = (const float*)d_in[3];
  const float* bsl = (const float*)d_in[4];
  const float* W0 = (const float*)d_in[5];
  const float* b0 = (const float*)d_in[6];
  const float* W1 = (const float*)d_in[7];
  const float* b1 = (const float*)d_in[8];
  const float* Wg = (const float*)d_in[9];
  const float* bg = (const float*)d_in[10];
  int n = in_sizes[0] / 128;
  int E = in_sizes[2];
  const int* row = eidx;
  const int* col = eidx + E;
  int n2 = 2 * n;

  char* w = (char*)d_ws;
  int* deg = (int*)w;             w += (size_t)n2 * 4;
  float* dinv = (float*)w;        w += (size_t)n2 * 4;
  int* row_start = (int*)w;       w += (size_t)n2 * 4;
  int* partials = (int*)w;        w += 1024;
  unsigned int* ebuf = (unsigned int*)w;  w += (size_t)E * 4;
  int* erank = (int*)w;           w += (size_t)E * 4;
  unsigned short* Wp3 = (unsigned short*)w;  w += 3 * 128 * 128 * 2;
  unsigned short* Wgp = (unsigned short*)w;  w += 384 * 128 * 2;
  unsigned short* hx = (unsigned short*)w;   w += (size_t)n * 128 * 2;
  unsigned short* h0 = (unsigned short*)w;   w += (size_t)n * 128 * 2;
  unsigned short* h1 = (unsigned short*)w;   w += (size_t)n * 128 * 2;
  unsigned short* xn = (unsigned short*)w;   w += (size_t)n * 128 * 2;
  unsigned short* xd = (unsigned short*)w;
  float* out = (float*)d_out;

  hipMemsetAsync(deg, 0, (size_t)n2 * 4, stream);

  int cd_blocks = (E + 255) / 256;
  pack_count<<<48 + cd_blocks, 256, 0, stream>>>(Wsl, W0, W1, Wg, Wp3, Wgp,
                                                 col, etype, deg, erank, E, n);
  int nb = (n2 + 2047) / 2048;
  dinv_scan1<<<nb + (n2 + 255) / 256, 256, 0, stream>>>(deg, dinv, partials, n2, nb);
  scan3b<<<nb, 256, 0, stream>>>(partials, deg, row_start, n2, nb);

  int gemm_blocks = (n + 63) / 64;
  gemm3_fill<<<gemm_blocks + cd_blocks, 256, 0, stream>>>(
      x, Wp3, bsl, hx, h0, h1, row, col, etype, erank, row_start, dinv, ebuf,
      n, E, gemm_blocks);

  int ga_blocks = (int)(((long long)n * 8 + 255) / 256);
  gather2<<<dim3(ga_blocks, 2), 256, 0, stream>>>(h0, h1, ebuf, row_start, deg, dinv,
                                                  b0, b1, xn, xd, n);
  gate_combine<<<(n + 15) / 16, 64, 0, stream>>>(hx, xn, xd, Wgp, bg, out, n);
}